// Round 1
// baseline (457.183 us; speedup 1.0000x reference)
//
#include <hip/hip_runtime.h>
#include <hip/hip_bf16.h>
#include <math.h>

#define D 128
#define NH 8
#define EPS 1e-12f

// ---------------- CSR build ----------------

__global__ void count_kernel(const int* __restrict__ dst, int* __restrict__ counts, int E) {
    int e = blockIdx.x * 256 + threadIdx.x;
    if (e < E) atomicAdd(&counts[dst[e]], 1);
}

__device__ __forceinline__ int block_incl_scan256(int v, int tid, int* wsum) {
    int lane = tid & 63;
    int wid = tid >> 6;
#pragma unroll
    for (int off = 1; off < 64; off <<= 1) {
        int t = __shfl_up(v, off, 64);
        if (lane >= off) v += t;
    }
    if (lane == 63) wsum[wid] = v;
    __syncthreads();
#pragma unroll
    for (int w = 0; w < 4; ++w) {
        if (w < wid) v += wsum[w];
    }
    return v;
}

// local inclusive scan per 256-chunk; offsets[i+1] = local inclusive, chunksum[b] = chunk total
__global__ void scan1_kernel(const int* __restrict__ counts, int* __restrict__ offsets,
                             int* __restrict__ chunksum, int n) {
    __shared__ int wsum[4];
    int tid = threadIdx.x;
    int i = blockIdx.x * 256 + tid;
    int v = (i < n) ? counts[i] : 0;
    int incl = block_incl_scan256(v, tid, wsum);
    if (i < n) offsets[i + 1] = incl;
    if (tid == 255) chunksum[blockIdx.x] = incl;
}

// single block: exclusive scan of chunk sums (nchunks <= 256)
__global__ void scan2_kernel(const int* __restrict__ chunksum, int* __restrict__ chunkbase, int nchunks) {
    __shared__ int wsum[4];
    int tid = threadIdx.x;
    int v = (tid < nchunks) ? chunksum[tid] : 0;
    int incl = block_incl_scan256(v, tid, wsum);
    if (tid < nchunks) chunkbase[tid] = incl - v;
}

// finalize offsets, init cursor[i] = offsets[i]
__global__ void scan3_kernel(const int* __restrict__ counts, int* __restrict__ offsets,
                             const int* __restrict__ chunkbase, int* __restrict__ cursor, int n) {
    int i = blockIdx.x * 256 + threadIdx.x;
    if (i < n) {
        int fin = offsets[i + 1] + chunkbase[blockIdx.x];
        offsets[i + 1] = fin;
        cursor[i] = fin - counts[i];
        if (i == 0) offsets[0] = 0;
    }
}

__global__ void fill_kernel(const int* __restrict__ dst, int* __restrict__ cursor,
                            int* __restrict__ perm, int E) {
    int e = blockIdx.x * 256 + threadIdx.x;
    if (e < E) {
        int d = dst[e];
        int pos = atomicAdd(&cursor[d], 1);
        perm[pos] = e;
    }
}

// ---------------- QKV projection GEMM ----------------
// grid (ceil(N/64), 3), block 256 (16x16). Each block: 64 rows x 128 cols of one of Q/K/V.
__global__ __launch_bounds__(256) void qkv_gemm_kernel(
    const float* __restrict__ h,
    const float* __restrict__ Wq, const float* __restrict__ bq,
    const float* __restrict__ Wk, const float* __restrict__ bk,
    const float* __restrict__ Wv, const float* __restrict__ bv,
    float* __restrict__ Q, float* __restrict__ K, float* __restrict__ V, int n) {
    __shared__ float hs[64][132];  // +4 pad: rows 4 apart land 16 banks apart
    int tid = threadIdx.x;
    int n0 = blockIdx.x * 64;
    // stage h tile (64x128) to LDS, zero-fill OOB rows
#pragma unroll
    for (int it = 0; it < 8; ++it) {
        int f4 = it * 256 + tid;        // float4 index, 0..2047
        int row = f4 >> 5;              // 32 float4 per row
        int c4 = (f4 & 31) * 4;
        float4 val = make_float4(0.f, 0.f, 0.f, 0.f);
        if (n0 + row < n) val = *(const float4*)&h[(size_t)(n0 + row) * D + c4];
        *(float4*)&hs[row][c4] = val;
    }
    __syncthreads();

    const float* W;
    const float* b;
    float* O;
    if (blockIdx.y == 0)      { W = Wq; b = bq; O = Q; }
    else if (blockIdx.y == 1) { W = Wk; b = bk; O = K; }
    else                      { W = Wv; b = bv; O = V; }

    int tx = tid & 15, ty = tid >> 4;
    int colbase = tx * 8;
    float acc[4][8] = {};

#pragma unroll 4
    for (int k = 0; k < D; ++k) {
        float4 w0 = *(const float4*)&W[k * D + colbase];
        float4 w1 = *(const float4*)&W[k * D + colbase + 4];
#pragma unroll
        for (int r = 0; r < 4; ++r) {
            float a = hs[ty * 4 + r][k];
            acc[r][0] = fmaf(a, w0.x, acc[r][0]);
            acc[r][1] = fmaf(a, w0.y, acc[r][1]);
            acc[r][2] = fmaf(a, w0.z, acc[r][2]);
            acc[r][3] = fmaf(a, w0.w, acc[r][3]);
            acc[r][4] = fmaf(a, w1.x, acc[r][4]);
            acc[r][5] = fmaf(a, w1.y, acc[r][5]);
            acc[r][6] = fmaf(a, w1.z, acc[r][6]);
            acc[r][7] = fmaf(a, w1.w, acc[r][7]);
        }
    }

    float4 b0 = *(const float4*)&b[colbase];
    float4 b1 = *(const float4*)&b[colbase + 4];
#pragma unroll
    for (int r = 0; r < 4; ++r) {
        int row = n0 + ty * 4 + r;
        if (row < n) {
            float4 o0 = make_float4(acc[r][0] + b0.x, acc[r][1] + b0.y,
                                    acc[r][2] + b0.z, acc[r][3] + b0.w);
            float4 o1 = make_float4(acc[r][4] + b1.x, acc[r][5] + b1.y,
                                    acc[r][6] + b1.z, acc[r][7] + b1.w);
            *(float4*)&O[(size_t)row * D + colbase] = o0;
            *(float4*)&O[(size_t)row * D + colbase + 4] = o1;
        }
    }
}

// ---------------- Edge attention: one wave per dst node, online softmax ----------------
__global__ __launch_bounds__(256) void edge_attn_kernel(
    const float* __restrict__ Q, const float* __restrict__ K, const float* __restrict__ V,
    const int* __restrict__ offsets, const int* __restrict__ perm,
    const int* __restrict__ src, float* __restrict__ agg, int n) {
    int wave = (blockIdx.x * 256 + threadIdx.x) >> 6;
    int lane = threadIdx.x & 63;
    if (wave >= n) return;
    int node = wave;
    int start = offsets[node];
    int end = offsets[node + 1];

    float2 q = *(const float2*)&Q[(size_t)node * D + lane * 2];
    float m = -INFINITY;
    float l = 0.f;
    float ax = 0.f, ay = 0.f;

    for (int base = start; base < end; base += 64) {
        int cnt = min(64, end - base);
        int sreg = 0;
        if (lane < cnt) {
            int e = perm[base + lane];
            sreg = src[e];
        }
        for (int j = 0; j < cnt; ++j) {
            int s = __shfl(sreg, j, 64);
            float2 kv = *(const float2*)&K[(size_t)s * D + lane * 2];
            float2 vv = *(const float2*)&V[(size_t)s * D + lane * 2];
            float part = kv.x * q.x + kv.y * q.y;
            // reduce within the 8-lane head group (lanes h*8..h*8+7 cover 16 dims)
            part += __shfl_xor(part, 1, 64);
            part += __shfl_xor(part, 2, 64);
            part += __shfl_xor(part, 4, 64);
            float sc = part;
            float mn = fmaxf(m, sc);
            float scale = __expf(m - mn);   // first edge: exp(-inf)=0
            float p = __expf(sc - mn);
            l = l * scale + p;
            ax = ax * scale + p * vv.x;
            ay = ay * scale + p * vv.y;
            m = mn;
        }
    }
    float inv = (l > 0.f) ? 1.f / l : 0.f;
    *(float2*)&agg[(size_t)node * D + lane * 2] = make_float2(ax * inv, ay * inv);
}

// ---------------- Output GEMM + bias + residual + LayerNorm ----------------
__global__ __launch_bounds__(256) void out_gemm_ln_kernel(
    const float* __restrict__ agg, const float* __restrict__ Wo, const float* __restrict__ bo,
    const float* __restrict__ hres, const float* __restrict__ gamma, const float* __restrict__ beta,
    float* __restrict__ out, int n) {
    __shared__ float as[64][132];
    __shared__ float red1[64][16];
    __shared__ float red2[64][16];
    int tid = threadIdx.x;
    int n0 = blockIdx.x * 64;
#pragma unroll
    for (int it = 0; it < 8; ++it) {
        int f4 = it * 256 + tid;
        int row = f4 >> 5;
        int c4 = (f4 & 31) * 4;
        float4 val = make_float4(0.f, 0.f, 0.f, 0.f);
        if (n0 + row < n) val = *(const float4*)&agg[(size_t)(n0 + row) * D + c4];
        *(float4*)&as[row][c4] = val;
    }
    __syncthreads();

    int tx = tid & 15, ty = tid >> 4;
    int colbase = tx * 8;
    float acc[4][8] = {};

#pragma unroll 4
    for (int k = 0; k < D; ++k) {
        float4 w0 = *(const float4*)&Wo[k * D + colbase];
        float4 w1 = *(const float4*)&Wo[k * D + colbase + 4];
#pragma unroll
        for (int r = 0; r < 4; ++r) {
            float a = as[ty * 4 + r][k];
            acc[r][0] = fmaf(a, w0.x, acc[r][0]);
            acc[r][1] = fmaf(a, w0.y, acc[r][1]);
            acc[r][2] = fmaf(a, w0.z, acc[r][2]);
            acc[r][3] = fmaf(a, w0.w, acc[r][3]);
            acc[r][4] = fmaf(a, w1.x, acc[r][4]);
            acc[r][5] = fmaf(a, w1.y, acc[r][5]);
            acc[r][6] = fmaf(a, w1.z, acc[r][6]);
            acc[r][7] = fmaf(a, w1.w, acc[r][7]);
        }
    }

    float4 bo0 = *(const float4*)&bo[colbase];
    float4 bo1 = *(const float4*)&bo[colbase + 4];
    float bb[8] = {bo0.x, bo0.y, bo0.z, bo0.w, bo1.x, bo1.y, bo1.z, bo1.w};
    float y[4][8];
#pragma unroll
    for (int r = 0; r < 4; ++r) {
        int lr = ty * 4 + r;
        int row = n0 + lr;
        float4 h0 = make_float4(0.f, 0.f, 0.f, 0.f), h1 = h0;
        if (row < n) {
            h0 = *(const float4*)&hres[(size_t)row * D + colbase];
            h1 = *(const float4*)&hres[(size_t)row * D + colbase + 4];
        }
        float hh[8] = {h0.x, h0.y, h0.z, h0.w, h1.x, h1.y, h1.z, h1.w};
        float s1 = 0.f, s2 = 0.f;
#pragma unroll
        for (int c = 0; c < 8; ++c) {
            float v = acc[r][c] + bb[c] + hh[c];
            y[r][c] = v;
            s1 += v;
            s2 += v * v;
        }
        red1[lr][tx] = s1;
        red2[lr][tx] = s2;
    }
    __syncthreads();

    float4 g0 = *(const float4*)&gamma[colbase];
    float4 g1 = *(const float4*)&gamma[colbase + 4];
    float4 be0 = *(const float4*)&beta[colbase];
    float4 be1 = *(const float4*)&beta[colbase + 4];
    float gg[8] = {g0.x, g0.y, g0.z, g0.w, g1.x, g1.y, g1.z, g1.w};
    float bt[8] = {be0.x, be0.y, be0.z, be0.w, be1.x, be1.y, be1.z, be1.w};

#pragma unroll
    for (int r = 0; r < 4; ++r) {
        int lr = ty * 4 + r;
        int row = n0 + lr;
        float S1 = 0.f, S2 = 0.f;
#pragma unroll
        for (int i = 0; i < 16; ++i) {
            S1 += red1[lr][i];
            S2 += red2[lr][i];
        }
        float mu = S1 * (1.f / 128.f);
        float var = S2 * (1.f / 128.f) - mu * mu;
        float rs = rsqrtf(fmaxf(var, 0.f) + EPS);
        if (row < n) {
            float o[8];
#pragma unroll
            for (int c = 0; c < 8; ++c) o[c] = (y[r][c] - mu) * rs * gg[c] + bt[c];
            *(float4*)&out[(size_t)row * D + colbase] = make_float4(o[0], o[1], o[2], o[3]);
            *(float4*)&out[(size_t)row * D + colbase + 4] = make_float4(o[4], o[5], o[6], o[7]);
        }
    }
}

// ---------------- launch ----------------
extern "C" void kernel_launch(void* const* d_in, const int* in_sizes, int n_in,
                              void* d_out, int out_size, void* d_ws, size_t ws_size,
                              hipStream_t stream) {
    const float* h     = (const float*)d_in[0];
    const float* Wq    = (const float*)d_in[1];
    const float* bq    = (const float*)d_in[2];
    const float* Wk    = (const float*)d_in[3];
    const float* bk    = (const float*)d_in[4];
    const float* Wv    = (const float*)d_in[5];
    const float* bv    = (const float*)d_in[6];
    const float* Wo    = (const float*)d_in[7];
    const float* bo    = (const float*)d_in[8];
    const float* gamma = (const float*)d_in[9];
    const float* beta  = (const float*)d_in[10];
    const int* src     = (const int*)d_in[11];
    const int* dst     = (const int*)d_in[12];
    float* out = (float*)d_out;

    int N = in_sizes[0] / D;
    int E = in_sizes[11];

    // workspace layout
    float* Qm = (float*)d_ws;
    float* Km = Qm + (size_t)N * D;
    float* Vm = Km + (size_t)N * D;
    int* counts   = (int*)(Vm + (size_t)N * D);
    int* offsets  = counts + N;
    int* cursor   = offsets + (N + 1);
    int* chunksum = cursor + N;
    int* chunkbase = chunksum + 512;
    int* perm     = chunkbase + 512;

    int nchunks = (N + 255) / 256;

    hipMemsetAsync(counts, 0, (size_t)N * sizeof(int), stream);
    count_kernel<<<(E + 255) / 256, 256, 0, stream>>>(dst, counts, E);
    scan1_kernel<<<nchunks, 256, 0, stream>>>(counts, offsets, chunksum, N);
    scan2_kernel<<<1, 256, 0, stream>>>(chunksum, chunkbase, nchunks);
    scan3_kernel<<<nchunks, 256, 0, stream>>>(counts, offsets, chunkbase, cursor, N);
    fill_kernel<<<(E + 255) / 256, 256, 0, stream>>>(dst, cursor, perm, E);

    dim3 qkv_grid((N + 63) / 64, 3);
    qkv_gemm_kernel<<<qkv_grid, 256, 0, stream>>>(h, Wq, bq, Wk, bk, Wv, bv, Qm, Km, Vm, N);

    edge_attn_kernel<<<(N + 3) / 4, 256, 0, stream>>>(Qm, Km, Vm, offsets, perm, src, out, N);

    out_gemm_ln_kernel<<<(N + 63) / 64, 256, 0, stream>>>(out, Wo, bo, h, gamma, beta, out, N);
}

// Round 2
// 372.606 us; speedup vs baseline: 1.2270x; 1.2270x over previous
//
#include <hip/hip_runtime.h>
#include <hip/hip_bf16.h>
#include <math.h>

#define D 128
#define NH 8
#define EPS 1e-12f

// float -> bf16 round-to-nearest-even (finite inputs)
__device__ __forceinline__ unsigned short f2bf(float f) {
    unsigned int u = __float_as_uint(f);
    unsigned int r = (u + 0x7fffu + ((u >> 16) & 1u)) >> 16;
    return (unsigned short)r;
}
__device__ __forceinline__ float bf2f_lo(unsigned int packed) {
    return __uint_as_float(packed << 16);
}
__device__ __forceinline__ float bf2f_hi(unsigned int packed) {
    return __uint_as_float(packed & 0xffff0000u);
}

// ---------------- CSR build ----------------

__global__ void count_kernel(const int* __restrict__ dst, int* __restrict__ counts, int E) {
    int e = blockIdx.x * 256 + threadIdx.x;
    if (e < E) atomicAdd(&counts[dst[e]], 1);
}

__device__ __forceinline__ int block_incl_scan256(int v, int tid, int* wsum) {
    int lane = tid & 63;
    int wid = tid >> 6;
#pragma unroll
    for (int off = 1; off < 64; off <<= 1) {
        int t = __shfl_up(v, off, 64);
        if (lane >= off) v += t;
    }
    if (lane == 63) wsum[wid] = v;
    __syncthreads();
#pragma unroll
    for (int w = 0; w < 4; ++w) {
        if (w < wid) v += wsum[w];
    }
    return v;
}

__global__ void scan1_kernel(const int* __restrict__ counts, int* __restrict__ offsets,
                             int* __restrict__ chunksum, int n) {
    __shared__ int wsum[4];
    int tid = threadIdx.x;
    int i = blockIdx.x * 256 + tid;
    int v = (i < n) ? counts[i] : 0;
    int incl = block_incl_scan256(v, tid, wsum);
    if (i < n) offsets[i + 1] = incl;
    if (tid == 255) chunksum[blockIdx.x] = incl;
}

__global__ void scan2_kernel(const int* __restrict__ chunksum, int* __restrict__ chunkbase, int nchunks) {
    __shared__ int wsum[4];
    int tid = threadIdx.x;
    int v = (tid < nchunks) ? chunksum[tid] : 0;
    int incl = block_incl_scan256(v, tid, wsum);
    if (tid < nchunks) chunkbase[tid] = incl - v;
}

__global__ void scan3_kernel(const int* __restrict__ counts, int* __restrict__ offsets,
                             const int* __restrict__ chunkbase, int* __restrict__ cursor, int n) {
    int i = blockIdx.x * 256 + threadIdx.x;
    if (i < n) {
        int fin = offsets[i + 1] + chunkbase[blockIdx.x];
        offsets[i + 1] = fin;
        cursor[i] = fin - counts[i];
        if (i == 0) offsets[0] = 0;
    }
}

// store src[e] directly so the hot kernel skips one random gather
__global__ void fill_kernel(const int* __restrict__ dst, const int* __restrict__ src,
                            int* __restrict__ cursor, int* __restrict__ psrc, int E) {
    int e = blockIdx.x * 256 + threadIdx.x;
    if (e < E) {
        int d = dst[e];
        int pos = atomicAdd(&cursor[d], 1);
        psrc[pos] = src[e];
    }
}

// ---------------- QKV projection GEMM ----------------
// grid (ceil(N/64), 3), block 256 (16x16). y=0 -> Q (fp32), y=1 -> K (bf16), y=2 -> V (bf16)
__global__ __launch_bounds__(256) void qkv_gemm_kernel(
    const float* __restrict__ h,
    const float* __restrict__ Wq, const float* __restrict__ bq,
    const float* __restrict__ Wk, const float* __restrict__ bk,
    const float* __restrict__ Wv, const float* __restrict__ bv,
    float* __restrict__ Q, unsigned short* __restrict__ Kb,
    unsigned short* __restrict__ Vb, int n) {
    __shared__ float hs[64][132];
    int tid = threadIdx.x;
    int n0 = blockIdx.x * 64;
#pragma unroll
    for (int it = 0; it < 8; ++it) {
        int f4 = it * 256 + tid;
        int row = f4 >> 5;
        int c4 = (f4 & 31) * 4;
        float4 val = make_float4(0.f, 0.f, 0.f, 0.f);
        if (n0 + row < n) val = *(const float4*)&h[(size_t)(n0 + row) * D + c4];
        *(float4*)&hs[row][c4] = val;
    }
    __syncthreads();

    const float* W;
    const float* b;
    if (blockIdx.y == 0)      { W = Wq; b = bq; }
    else if (blockIdx.y == 1) { W = Wk; b = bk; }
    else                      { W = Wv; b = bv; }

    int tx = tid & 15, ty = tid >> 4;
    int colbase = tx * 8;
    float acc[4][8] = {};

#pragma unroll 4
    for (int k = 0; k < D; ++k) {
        float4 w0 = *(const float4*)&W[k * D + colbase];
        float4 w1 = *(const float4*)&W[k * D + colbase + 4];
#pragma unroll
        for (int r = 0; r < 4; ++r) {
            float a = hs[ty * 4 + r][k];
            acc[r][0] = fmaf(a, w0.x, acc[r][0]);
            acc[r][1] = fmaf(a, w0.y, acc[r][1]);
            acc[r][2] = fmaf(a, w0.z, acc[r][2]);
            acc[r][3] = fmaf(a, w0.w, acc[r][3]);
            acc[r][4] = fmaf(a, w1.x, acc[r][4]);
            acc[r][5] = fmaf(a, w1.y, acc[r][5]);
            acc[r][6] = fmaf(a, w1.z, acc[r][6]);
            acc[r][7] = fmaf(a, w1.w, acc[r][7]);
        }
    }

    float4 b0 = *(const float4*)&b[colbase];
    float4 b1 = *(const float4*)&b[colbase + 4];
    float bb[8] = {b0.x, b0.y, b0.z, b0.w, b1.x, b1.y, b1.z, b1.w};

    if (blockIdx.y == 0) {
#pragma unroll
        for (int r = 0; r < 4; ++r) {
            int row = n0 + ty * 4 + r;
            if (row < n) {
                float o[8];
#pragma unroll
                for (int c = 0; c < 8; ++c) o[c] = acc[r][c] + bb[c];
                *(float4*)&Q[(size_t)row * D + colbase] = make_float4(o[0], o[1], o[2], o[3]);
                *(float4*)&Q[(size_t)row * D + colbase + 4] = make_float4(o[4], o[5], o[6], o[7]);
            }
        }
    } else {
        unsigned short* Ob = (blockIdx.y == 1) ? Kb : Vb;
#pragma unroll
        for (int r = 0; r < 4; ++r) {
            int row = n0 + ty * 4 + r;
            if (row < n) {
                union { unsigned short u[8]; uint4 v4; } pk;
#pragma unroll
                for (int c = 0; c < 8; ++c) pk.u[c] = f2bf(acc[r][c] + bb[c]);
                *(uint4*)&Ob[(size_t)row * D + colbase] = pk.v4;
            }
        }
    }
}

// ---------------- Edge attention: one wave per dst node, 2-way interleaved online softmax ----------------
__global__ __launch_bounds__(256) void edge_attn_kernel(
    const float* __restrict__ Q, const unsigned short* __restrict__ Kb,
    const unsigned short* __restrict__ Vb,
    const int* __restrict__ offsets, const int* __restrict__ psrc,
    float* __restrict__ agg, int n) {
    int wave = (blockIdx.x * 256 + threadIdx.x) >> 6;
    int lane = threadIdx.x & 63;
    if (wave >= n) return;
    int start = offsets[wave];
    int end = offsets[wave + 1];

    float2 q = *(const float2*)&Q[(size_t)wave * D + lane * 2];

    // two independent online-softmax states (even edges -> A, odd -> B)
    float mA = -INFINITY, lA = 0.f, axA = 0.f, ayA = 0.f;
    float mB = -INFINITY, lB = 0.f, axB = 0.f, ayB = 0.f;

    for (int base = start; base < end; base += 64) {
        int cnt = min(64, end - base);
        int sreg = (lane < cnt) ? psrc[base + lane] : 0;
        int j = 0;
        for (; j + 2 <= cnt; j += 2) {
            int s0 = __shfl(sreg, j, 64);
            int s1 = __shfl(sreg, j + 1, 64);
            unsigned int k0u = *(const unsigned int*)&Kb[(size_t)s0 * D + lane * 2];
            unsigned int v0u = *(const unsigned int*)&Vb[(size_t)s0 * D + lane * 2];
            unsigned int k1u = *(const unsigned int*)&Kb[(size_t)s1 * D + lane * 2];
            unsigned int v1u = *(const unsigned int*)&Vb[(size_t)s1 * D + lane * 2];

            float p0 = fmaf(bf2f_hi(k0u), q.y, bf2f_lo(k0u) * q.x);
            float p1 = fmaf(bf2f_hi(k1u), q.y, bf2f_lo(k1u) * q.x);
            p0 += __shfl_xor(p0, 1, 64);
            p1 += __shfl_xor(p1, 1, 64);
            p0 += __shfl_xor(p0, 2, 64);
            p1 += __shfl_xor(p1, 2, 64);
            p0 += __shfl_xor(p0, 4, 64);
            p1 += __shfl_xor(p1, 4, 64);

            {
                float mn = fmaxf(mA, p0);
                float sc = __expf(mA - mn);
                float p = __expf(p0 - mn);
                lA = fmaf(lA, sc, p);
                axA = fmaf(axA, sc, p * bf2f_lo(v0u));
                ayA = fmaf(ayA, sc, p * bf2f_hi(v0u));
                mA = mn;
            }
            {
                float mn = fmaxf(mB, p1);
                float sc = __expf(mB - mn);
                float p = __expf(p1 - mn);
                lB = fmaf(lB, sc, p);
                axB = fmaf(axB, sc, p * bf2f_lo(v1u));
                ayB = fmaf(ayB, sc, p * bf2f_hi(v1u));
                mB = mn;
            }
        }
        if (j < cnt) {
            int s0 = __shfl(sreg, j, 64);
            unsigned int k0u = *(const unsigned int*)&Kb[(size_t)s0 * D + lane * 2];
            unsigned int v0u = *(const unsigned int*)&Vb[(size_t)s0 * D + lane * 2];
            float p0 = fmaf(bf2f_hi(k0u), q.y, bf2f_lo(k0u) * q.x);
            p0 += __shfl_xor(p0, 1, 64);
            p0 += __shfl_xor(p0, 2, 64);
            p0 += __shfl_xor(p0, 4, 64);
            float mn = fmaxf(mA, p0);
            float sc = __expf(mA - mn);
            float p = __expf(p0 - mn);
            lA = fmaf(lA, sc, p);
            axA = fmaf(axA, sc, p * bf2f_lo(v0u));
            ayA = fmaf(ayA, sc, p * bf2f_hi(v0u));
            mA = mn;
        }
    }

    // merge B into A (guard: empty B would give exp(-inf - -inf) = nan)
    if (mB > -INFINITY) {
        float mn = fmaxf(mA, mB);
        float sA = __expf(mA - mn);
        float sB = __expf(mB - mn);
        lA = lA * sA + lB * sB;
        axA = axA * sA + axB * sB;
        ayA = ayA * sA + ayB * sB;
    }
    float inv = (lA > 0.f) ? 1.f / lA : 0.f;
    *(float2*)&agg[(size_t)wave * D + lane * 2] = make_float2(axA * inv, ayA * inv);
}

// ---------------- Output GEMM + bias + residual + LayerNorm ----------------
__global__ __launch_bounds__(256) void out_gemm_ln_kernel(
    const float* __restrict__ agg, const float* __restrict__ Wo, const float* __restrict__ bo,
    const float* __restrict__ hres, const float* __restrict__ gamma, const float* __restrict__ beta,
    float* __restrict__ out, int n) {
    __shared__ float as[64][132];
    __shared__ float red1[64][16];
    __shared__ float red2[64][16];
    int tid = threadIdx.x;
    int n0 = blockIdx.x * 64;
#pragma unroll
    for (int it = 0; it < 8; ++it) {
        int f4 = it * 256 + tid;
        int row = f4 >> 5;
        int c4 = (f4 & 31) * 4;
        float4 val = make_float4(0.f, 0.f, 0.f, 0.f);
        if (n0 + row < n) val = *(const float4*)&agg[(size_t)(n0 + row) * D + c4];
        *(float4*)&as[row][c4] = val;
    }
    __syncthreads();

    int tx = tid & 15, ty = tid >> 4;
    int colbase = tx * 8;
    float acc[4][8] = {};

#pragma unroll 4
    for (int k = 0; k < D; ++k) {
        float4 w0 = *(const float4*)&Wo[k * D + colbase];
        float4 w1 = *(const float4*)&Wo[k * D + colbase + 4];
#pragma unroll
        for (int r = 0; r < 4; ++r) {
            float a = as[ty * 4 + r][k];
            acc[r][0] = fmaf(a, w0.x, acc[r][0]);
            acc[r][1] = fmaf(a, w0.y, acc[r][1]);
            acc[r][2] = fmaf(a, w0.z, acc[r][2]);
            acc[r][3] = fmaf(a, w0.w, acc[r][3]);
            acc[r][4] = fmaf(a, w1.x, acc[r][4]);
            acc[r][5] = fmaf(a, w1.y, acc[r][5]);
            acc[r][6] = fmaf(a, w1.z, acc[r][6]);
            acc[r][7] = fmaf(a, w1.w, acc[r][7]);
        }
    }

    float4 bo0 = *(const float4*)&bo[colbase];
    float4 bo1 = *(const float4*)&bo[colbase + 4];
    float bb[8] = {bo0.x, bo0.y, bo0.z, bo0.w, bo1.x, bo1.y, bo1.z, bo1.w};
    float y[4][8];
#pragma unroll
    for (int r = 0; r < 4; ++r) {
        int lr = ty * 4 + r;
        int row = n0 + lr;
        float4 h0 = make_float4(0.f, 0.f, 0.f, 0.f), h1 = h0;
        if (row < n) {
            h0 = *(const float4*)&hres[(size_t)row * D + colbase];
            h1 = *(const float4*)&hres[(size_t)row * D + colbase + 4];
        }
        float hh[8] = {h0.x, h0.y, h0.z, h0.w, h1.x, h1.y, h1.z, h1.w};
        float s1 = 0.f, s2 = 0.f;
#pragma unroll
        for (int c = 0; c < 8; ++c) {
            float v = acc[r][c] + bb[c] + hh[c];
            y[r][c] = v;
            s1 += v;
            s2 += v * v;
        }
        red1[lr][tx] = s1;
        red2[lr][tx] = s2;
    }
    __syncthreads();

    float4 g0 = *(const float4*)&gamma[colbase];
    float4 g1 = *(const float4*)&gamma[colbase + 4];
    float4 be0 = *(const float4*)&beta[colbase];
    float4 be1 = *(const float4*)&beta[colbase + 4];
    float gg[8] = {g0.x, g0.y, g0.z, g0.w, g1.x, g1.y, g1.z, g1.w};
    float bt[8] = {be0.x, be0.y, be0.z, be0.w, be1.x, be1.y, be1.z, be1.w};

#pragma unroll
    for (int r = 0; r < 4; ++r) {
        int lr = ty * 4 + r;
        int row = n0 + lr;
        float S1 = 0.f, S2 = 0.f;
#pragma unroll
        for (int i = 0; i < 16; ++i) {
            S1 += red1[lr][i];
            S2 += red2[lr][i];
        }
        float mu = S1 * (1.f / 128.f);
        float var = S2 * (1.f / 128.f) - mu * mu;
        float rs = rsqrtf(fmaxf(var, 0.f) + EPS);
        if (row < n) {
            float o[8];
#pragma unroll
            for (int c = 0; c < 8; ++c) o[c] = (y[r][c] - mu) * rs * gg[c] + bt[c];
            *(float4*)&out[(size_t)row * D + colbase] = make_float4(o[0], o[1], o[2], o[3]);
            *(float4*)&out[(size_t)row * D + colbase + 4] = make_float4(o[4], o[5], o[6], o[7]);
        }
    }
}

// ---------------- launch ----------------
extern "C" void kernel_launch(void* const* d_in, const int* in_sizes, int n_in,
                              void* d_out, int out_size, void* d_ws, size_t ws_size,
                              hipStream_t stream) {
    const float* h     = (const float*)d_in[0];
    const float* Wq    = (const float*)d_in[1];
    const float* bq    = (const float*)d_in[2];
    const float* Wk    = (const float*)d_in[3];
    const float* bk    = (const float*)d_in[4];
    const float* Wv    = (const float*)d_in[5];
    const float* bv    = (const float*)d_in[6];
    const float* Wo    = (const float*)d_in[7];
    const float* bo    = (const float*)d_in[8];
    const float* gamma = (const float*)d_in[9];
    const float* beta  = (const float*)d_in[10];
    const int* src     = (const int*)d_in[11];
    const int* dst     = (const int*)d_in[12];
    float* out = (float*)d_out;

    int N = in_sizes[0] / D;
    int E = in_sizes[11];

    // workspace layout
    float* Qm = (float*)d_ws;
    unsigned short* Km = (unsigned short*)(Qm + (size_t)N * D);
    unsigned short* Vm = Km + (size_t)N * D;
    int* counts   = (int*)(Vm + (size_t)N * D);
    int* offsets  = counts + N;
    int* cursor   = offsets + (N + 1);
    int* chunksum = cursor + N;
    int* chunkbase = chunksum + 512;
    int* psrc     = chunkbase + 512;

    int nchunks = (N + 255) / 256;

    hipMemsetAsync(counts, 0, (size_t)N * sizeof(int), stream);
    count_kernel<<<(E + 255) / 256, 256, 0, stream>>>(dst, counts, E);
    scan1_kernel<<<nchunks, 256, 0, stream>>>(counts, offsets, chunksum, N);
    scan2_kernel<<<1, 256, 0, stream>>>(chunksum, chunkbase, nchunks);
    scan3_kernel<<<nchunks, 256, 0, stream>>>(counts, offsets, chunkbase, cursor, N);
    fill_kernel<<<(E + 255) / 256, 256, 0, stream>>>(dst, src, cursor, psrc, E);

    dim3 qkv_grid((N + 63) / 64, 3);
    qkv_gemm_kernel<<<qkv_grid, 256, 0, stream>>>(h, Wq, bq, Wk, bk, Wv, bv, Qm, Km, Vm, N);

    edge_attn_kernel<<<(N + 3) / 4, 256, 0, stream>>>(Qm, Km, Vm, offsets, psrc, out, N);

    out_gemm_ln_kernel<<<(N + 63) / 64, 256, 0, stream>>>(out, Wo, bo, h, gamma, beta, out, N);
}

// Round 3
// 310.156 us; speedup vs baseline: 1.4740x; 1.2013x over previous
//
#include <hip/hip_runtime.h>
#include <hip/hip_bf16.h>
#include <math.h>

#define D 128
#define EPS 1e-12f

typedef __attribute__((ext_vector_type(8))) short bf16x8;
typedef __attribute__((ext_vector_type(4))) float f32x4;

// float -> bf16 round-to-nearest-even (finite inputs)
__device__ __forceinline__ unsigned short f2bf(float f) {
    unsigned int u = __float_as_uint(f);
    return (unsigned short)((u + 0x7fffu + ((u >> 16) & 1u)) >> 16);
}
__device__ __forceinline__ float bf2f_lo(unsigned int packed) {
    return __uint_as_float(packed << 16);
}
__device__ __forceinline__ float bf2f_hi(unsigned int packed) {
    return __uint_as_float(packed & 0xffff0000u);
}

// ---------------- CSR build ----------------

__global__ void count_kernel(const int* __restrict__ dst, int* __restrict__ counts, int E) {
    int e = blockIdx.x * 256 + threadIdx.x;
    if (e < E) atomicAdd(&counts[dst[e]], 1);
}

__device__ __forceinline__ int block_incl_scan256(int v, int tid, int* wsum) {
    int lane = tid & 63;
    int wid = tid >> 6;
#pragma unroll
    for (int off = 1; off < 64; off <<= 1) {
        int t = __shfl_up(v, off, 64);
        if (lane >= off) v += t;
    }
    if (lane == 63) wsum[wid] = v;
    __syncthreads();
#pragma unroll
    for (int w = 0; w < 4; ++w) {
        if (w < wid) v += wsum[w];
    }
    return v;
}

__global__ void scan1_kernel(const int* __restrict__ counts, int* __restrict__ offsets,
                             int* __restrict__ chunksum, int n) {
    __shared__ int wsum[4];
    int tid = threadIdx.x;
    int i = blockIdx.x * 256 + tid;
    int v = (i < n) ? counts[i] : 0;
    int incl = block_incl_scan256(v, tid, wsum);
    if (i < n) offsets[i + 1] = incl;
    if (tid == 255) chunksum[blockIdx.x] = incl;
}

__global__ void scan2_kernel(const int* __restrict__ chunksum, int* __restrict__ chunkbase, int nchunks) {
    __shared__ int wsum[4];
    int tid = threadIdx.x;
    int v = (tid < nchunks) ? chunksum[tid] : 0;
    int incl = block_incl_scan256(v, tid, wsum);
    if (tid < nchunks) chunkbase[tid] = incl - v;
}

__global__ void scan3_kernel(const int* __restrict__ counts, int* __restrict__ offsets,
                             const int* __restrict__ chunkbase, int* __restrict__ cursor, int n) {
    int i = blockIdx.x * 256 + threadIdx.x;
    if (i < n) {
        int fin = offsets[i + 1] + chunkbase[blockIdx.x];
        offsets[i + 1] = fin;
        cursor[i] = fin - counts[i];
        if (i == 0) offsets[0] = 0;
    }
}

__global__ void fill_kernel(const int* __restrict__ dst, const int* __restrict__ src,
                            int* __restrict__ cursor, int* __restrict__ psrc, int E) {
    int e = blockIdx.x * 256 + threadIdx.x;
    if (e < E) {
        int d = dst[e];
        int pos = atomicAdd(&cursor[d], 1);
        psrc[pos] = src[e];
    }
}

// ---------------- W convert + transpose: WT[m][n][k] bf16 ----------------
// grid (16, 4), block 256. blockIdx.x: (x&3)*32 = k-block, (x>>2)*32 = n-block
__global__ __launch_bounds__(256) void wconv_kernel(
    const float* __restrict__ Wq, const float* __restrict__ Wk,
    const float* __restrict__ Wv, const float* __restrict__ Wo,
    unsigned short* __restrict__ WT) {
    __shared__ unsigned short tile[32][33];
    int m = blockIdx.y;
    const float* W = (m == 0) ? Wq : (m == 1) ? Wk : (m == 2) ? Wv : Wo;
    int r0 = (blockIdx.x & 3) * 32;   // k
    int c0 = (blockIdx.x >> 2) * 32;  // n
    int tid = threadIdx.x;
    int row = tid >> 3, c4 = (tid & 7) * 4;
    float4 v = *(const float4*)&W[(size_t)(r0 + row) * D + c0 + c4];
    tile[c4 + 0][row] = f2bf(v.x);
    tile[c4 + 1][row] = f2bf(v.y);
    tile[c4 + 2][row] = f2bf(v.z);
    tile[c4 + 3][row] = f2bf(v.w);
    __syncthreads();
    unsigned int lo = (unsigned int)tile[row][c4] | ((unsigned int)tile[row][c4 + 1] << 16);
    unsigned int hi = (unsigned int)tile[row][c4 + 2] | ((unsigned int)tile[row][c4 + 3] << 16);
    uint2 pk; pk.x = lo; pk.y = hi;
    *(uint2*)&WT[((size_t)m * D + (c0 + row)) * D + r0 + c4] = pk;
}

// ---------------- QKV projection via MFMA ----------------
// grid ceil(N/64), block 256 (4 waves). Each block: 64 rows, all 3 matrices.
__global__ __launch_bounds__(256) void qkv_mfma_kernel(
    const float* __restrict__ h, const unsigned short* __restrict__ WT,
    const float* __restrict__ bq, const float* __restrict__ bk, const float* __restrict__ bv,
    float* __restrict__ Q, unsigned short* __restrict__ Kb,
    unsigned short* __restrict__ Vb, int n) {
    __shared__ __align__(16) unsigned short hs[64][136];
    __shared__ __align__(16) unsigned short wt[128][136];
    int tid = threadIdx.x;
    int n0 = blockIdx.x * 64;
    // stage h tile 64x128 -> bf16 LDS
#pragma unroll
    for (int it = 0; it < 8; ++it) {
        int f4 = it * 256 + tid;
        int row = f4 >> 5;
        int c4 = (f4 & 31) * 4;
        float4 v = make_float4(0.f, 0.f, 0.f, 0.f);
        if (n0 + row < n) v = *(const float4*)&h[(size_t)(n0 + row) * D + c4];
        uint2 pk;
        pk.x = (unsigned int)f2bf(v.x) | ((unsigned int)f2bf(v.y) << 16);
        pk.y = (unsigned int)f2bf(v.z) | ((unsigned int)f2bf(v.w) << 16);
        *(uint2*)&hs[row][c4] = pk;
    }

    int lane = tid & 63, wid = tid >> 6;
    int quad = lane >> 4, l15 = lane & 15;
    int rbase = wid * 16;

    for (int m = 0; m < 3; ++m) {
        // stage WT_m (bf16, [n][k] row-major, 128x128)
#pragma unroll
        for (int it = 0; it < 8; ++it) {
            int idx = it * 256 + tid;
            int row = idx >> 4;
            int c8 = (idx & 15) * 8;
            *(uint4*)&wt[row][c8] = *(const uint4*)&WT[((size_t)m * D + row) * D + c8];
        }
        __syncthreads();

        bf16x8 af[4];
#pragma unroll
        for (int ks = 0; ks < 4; ++ks)
            af[ks] = *(const bf16x8*)&hs[rbase + l15][ks * 32 + quad * 8];

        const float* bias = (m == 0) ? bq : (m == 1) ? bk : bv;
#pragma unroll
        for (int ct = 0; ct < 8; ++ct) {
            f32x4 acc = {0.f, 0.f, 0.f, 0.f};
#pragma unroll
            for (int ks = 0; ks < 4; ++ks) {
                bf16x8 bf = *(const bf16x8*)&wt[ct * 16 + l15][ks * 32 + quad * 8];
                acc = __builtin_amdgcn_mfma_f32_16x16x32_bf16(af[ks], bf, acc, 0, 0, 0);
            }
            int col = ct * 16 + l15;
            float bb = bias[col];
            if (m == 0) {
#pragma unroll
                for (int r = 0; r < 4; ++r) {
                    int row = n0 + rbase + quad * 4 + r;
                    if (row < n) Q[(size_t)row * D + col] = acc[r] + bb;
                }
            } else {
                unsigned short* Ob = (m == 1) ? Kb : Vb;
#pragma unroll
                for (int r = 0; r < 4; ++r) {
                    int row = n0 + rbase + quad * 4 + r;
                    if (row < n) Ob[(size_t)row * D + col] = f2bf(acc[r] + bb);
                }
            }
        }
        __syncthreads();
    }
}

// ---------------- Edge attention: one wave per dst node, 2-way interleaved online softmax ----------------
__global__ __launch_bounds__(256) void edge_attn_kernel(
    const float* __restrict__ Q, const unsigned short* __restrict__ Kb,
    const unsigned short* __restrict__ Vb,
    const int* __restrict__ offsets, const int* __restrict__ psrc,
    float* __restrict__ agg, int n) {
    int wave = (blockIdx.x * 256 + threadIdx.x) >> 6;
    int lane = threadIdx.x & 63;
    if (wave >= n) return;
    int start = offsets[wave];
    int end = offsets[wave + 1];

    float2 q = *(const float2*)&Q[(size_t)wave * D + lane * 2];

    float mA = -INFINITY, lA = 0.f, axA = 0.f, ayA = 0.f;
    float mB = -INFINITY, lB = 0.f, axB = 0.f, ayB = 0.f;

    for (int base = start; base < end; base += 64) {
        int cnt = min(64, end - base);
        int sreg = (lane < cnt) ? psrc[base + lane] : 0;
        int j = 0;
        for (; j + 2 <= cnt; j += 2) {
            int s0 = __shfl(sreg, j, 64);
            int s1 = __shfl(sreg, j + 1, 64);
            unsigned int k0u = *(const unsigned int*)&Kb[(size_t)s0 * D + lane * 2];
            unsigned int v0u = *(const unsigned int*)&Vb[(size_t)s0 * D + lane * 2];
            unsigned int k1u = *(const unsigned int*)&Kb[(size_t)s1 * D + lane * 2];
            unsigned int v1u = *(const unsigned int*)&Vb[(size_t)s1 * D + lane * 2];

            float p0 = fmaf(bf2f_hi(k0u), q.y, bf2f_lo(k0u) * q.x);
            float p1 = fmaf(bf2f_hi(k1u), q.y, bf2f_lo(k1u) * q.x);
            p0 += __shfl_xor(p0, 1, 64);
            p1 += __shfl_xor(p1, 1, 64);
            p0 += __shfl_xor(p0, 2, 64);
            p1 += __shfl_xor(p1, 2, 64);
            p0 += __shfl_xor(p0, 4, 64);
            p1 += __shfl_xor(p1, 4, 64);

            {
                float mn = fmaxf(mA, p0);
                float sc = __expf(mA - mn);
                float p = __expf(p0 - mn);
                lA = fmaf(lA, sc, p);
                axA = fmaf(axA, sc, p * bf2f_lo(v0u));
                ayA = fmaf(ayA, sc, p * bf2f_hi(v0u));
                mA = mn;
            }
            {
                float mn = fmaxf(mB, p1);
                float sc = __expf(mB - mn);
                float p = __expf(p1 - mn);
                lB = fmaf(lB, sc, p);
                axB = fmaf(axB, sc, p * bf2f_lo(v1u));
                ayB = fmaf(ayB, sc, p * bf2f_hi(v1u));
                mB = mn;
            }
        }
        if (j < cnt) {
            int s0 = __shfl(sreg, j, 64);
            unsigned int k0u = *(const unsigned int*)&Kb[(size_t)s0 * D + lane * 2];
            unsigned int v0u = *(const unsigned int*)&Vb[(size_t)s0 * D + lane * 2];
            float p0 = fmaf(bf2f_hi(k0u), q.y, bf2f_lo(k0u) * q.x);
            p0 += __shfl_xor(p0, 1, 64);
            p0 += __shfl_xor(p0, 2, 64);
            p0 += __shfl_xor(p0, 4, 64);
            float mn = fmaxf(mA, p0);
            float sc = __expf(mA - mn);
            float p = __expf(p0 - mn);
            lA = fmaf(lA, sc, p);
            axA = fmaf(axA, sc, p * bf2f_lo(v0u));
            ayA = fmaf(ayA, sc, p * bf2f_hi(v0u));
            mA = mn;
        }
    }

    if (mB > -INFINITY) {
        float mn = fmaxf(mA, mB);
        float sA = __expf(mA - mn);
        float sB = __expf(mB - mn);
        lA = lA * sA + lB * sB;
        axA = axA * sA + axB * sB;
        ayA = ayA * sA + ayB * sB;
    }
    float inv = (lA > 0.f) ? 1.f / lA : 0.f;
    *(float2*)&agg[(size_t)wave * D + lane * 2] = make_float2(axA * inv, ayA * inv);
}

// ---------------- Output GEMM (MFMA) + bias + residual + LayerNorm (in-register) ----------------
__global__ __launch_bounds__(256) void out_ln_mfma_kernel(
    const float* __restrict__ agg, const unsigned short* __restrict__ WTo,
    const float* __restrict__ bo, const float* __restrict__ hres,
    const float* __restrict__ gamma, const float* __restrict__ beta,
    float* __restrict__ out, int n) {
    __shared__ __align__(16) unsigned short as_[64][136];
    __shared__ __align__(16) unsigned short wt[128][136];
    int tid = threadIdx.x;
    int n0 = blockIdx.x * 64;
#pragma unroll
    for (int it = 0; it < 8; ++it) {
        int f4 = it * 256 + tid;
        int row = f4 >> 5;
        int c4 = (f4 & 31) * 4;
        float4 v = make_float4(0.f, 0.f, 0.f, 0.f);
        if (n0 + row < n) v = *(const float4*)&agg[(size_t)(n0 + row) * D + c4];
        uint2 pk;
        pk.x = (unsigned int)f2bf(v.x) | ((unsigned int)f2bf(v.y) << 16);
        pk.y = (unsigned int)f2bf(v.z) | ((unsigned int)f2bf(v.w) << 16);
        *(uint2*)&as_[row][c4] = pk;
    }
#pragma unroll
    for (int it = 0; it < 8; ++it) {
        int idx = it * 256 + tid;
        int row = idx >> 4;
        int c8 = (idx & 15) * 8;
        *(uint4*)&wt[row][c8] = *(const uint4*)&WTo[(size_t)row * D + c8];
    }
    __syncthreads();

    int lane = tid & 63, wid = tid >> 6;
    int quad = lane >> 4, l15 = lane & 15;
    int rbase = wid * 16;

    bf16x8 af[4];
#pragma unroll
    for (int ks = 0; ks < 4; ++ks)
        af[ks] = *(const bf16x8*)&as_[rbase + l15][ks * 32 + quad * 8];

    f32x4 acc[8];
#pragma unroll
    for (int ct = 0; ct < 8; ++ct) {
        acc[ct] = (f32x4){0.f, 0.f, 0.f, 0.f};
#pragma unroll
        for (int ks = 0; ks < 4; ++ks) {
            bf16x8 bf = *(const bf16x8*)&wt[ct * 16 + l15][ks * 32 + quad * 8];
            acc[ct] = __builtin_amdgcn_mfma_f32_16x16x32_bf16(af[ks], bf, acc[ct], 0, 0, 0);
        }
    }

    // y = acc + bo + h (residual); preload per-ct params
    float bb[8], gg[8], be[8];
#pragma unroll
    for (int ct = 0; ct < 8; ++ct) {
        int col = ct * 16 + l15;
        bb[ct] = bo[col];
        gg[ct] = gamma[col];
        be[ct] = beta[col];
    }
#pragma unroll
    for (int ct = 0; ct < 8; ++ct) {
        int col = ct * 16 + l15;
#pragma unroll
        for (int r = 0; r < 4; ++r) {
            int row = n0 + rbase + quad * 4 + r;
            float hv = (row < n) ? hres[(size_t)row * D + col] : 0.f;
            acc[ct][r] = acc[ct][r] + bb[ct] + hv;
        }
    }

    // LayerNorm per row: row lives in this quad's 16 lanes x 8 cts
#pragma unroll
    for (int r = 0; r < 4; ++r) {
        float s1 = 0.f, s2 = 0.f;
#pragma unroll
        for (int ct = 0; ct < 8; ++ct) {
            float v = acc[ct][r];
            s1 += v;
            s2 += v * v;
        }
        s1 += __shfl_xor(s1, 1, 64); s2 += __shfl_xor(s2, 1, 64);
        s1 += __shfl_xor(s1, 2, 64); s2 += __shfl_xor(s2, 2, 64);
        s1 += __shfl_xor(s1, 4, 64); s2 += __shfl_xor(s2, 4, 64);
        s1 += __shfl_xor(s1, 8, 64); s2 += __shfl_xor(s2, 8, 64);
        float mu = s1 * (1.f / 128.f);
        float var = s2 * (1.f / 128.f) - mu * mu;
        float rs = rsqrtf(fmaxf(var, 0.f) + EPS);
        int row = n0 + rbase + quad * 4 + r;
        if (row < n) {
#pragma unroll
            for (int ct = 0; ct < 8; ++ct) {
                int col = ct * 16 + l15;
                out[(size_t)row * D + col] = (acc[ct][r] - mu) * rs * gg[ct] + be[ct];
            }
        }
    }
}

// ---------------- launch ----------------
extern "C" void kernel_launch(void* const* d_in, const int* in_sizes, int n_in,
                              void* d_out, int out_size, void* d_ws, size_t ws_size,
                              hipStream_t stream) {
    const float* h     = (const float*)d_in[0];
    const float* Wq    = (const float*)d_in[1];
    const float* bq    = (const float*)d_in[2];
    const float* Wk    = (const float*)d_in[3];
    const float* bk    = (const float*)d_in[4];
    const float* Wv    = (const float*)d_in[5];
    const float* bv    = (const float*)d_in[6];
    const float* Wo    = (const float*)d_in[7];
    const float* bo    = (const float*)d_in[8];
    const float* gamma = (const float*)d_in[9];
    const float* beta  = (const float*)d_in[10];
    const int* src     = (const int*)d_in[11];
    const int* dst     = (const int*)d_in[12];
    float* out = (float*)d_out;

    int N = in_sizes[0] / D;
    int E = in_sizes[11];

    // workspace layout
    float* Qm = (float*)d_ws;
    unsigned short* Km = (unsigned short*)(Qm + (size_t)N * D);
    unsigned short* Vm = Km + (size_t)N * D;
    unsigned short* WT = Vm + (size_t)N * D;           // 4 * 128 * 128 bf16
    int* counts   = (int*)(WT + 4 * D * D);
    int* offsets  = counts + N;
    int* cursor   = offsets + (N + 1);
    int* chunksum = cursor + N;
    int* chunkbase = chunksum + 512;
    int* psrc     = chunkbase + 512;

    int nchunks = (N + 255) / 256;

    hipMemsetAsync(counts, 0, (size_t)N * sizeof(int), stream);
    wconv_kernel<<<dim3(16, 4), 256, 0, stream>>>(Wq, Wk, Wv, Wo, WT);
    count_kernel<<<(E + 255) / 256, 256, 0, stream>>>(dst, counts, E);
    scan1_kernel<<<nchunks, 256, 0, stream>>>(counts, offsets, chunksum, N);
    scan2_kernel<<<1, 256, 0, stream>>>(chunksum, chunkbase, nchunks);
    scan3_kernel<<<nchunks, 256, 0, stream>>>(counts, offsets, chunkbase, cursor, N);
    fill_kernel<<<(E + 255) / 256, 256, 0, stream>>>(dst, src, cursor, psrc, E);

    qkv_mfma_kernel<<<(N + 63) / 64, 256, 0, stream>>>(h, WT, bq, bk, bv, Qm, Km, Vm, N);

    edge_attn_kernel<<<(N + 3) / 4, 256, 0, stream>>>(Qm, Km, Vm, offsets, psrc, out, N);

    out_ln_mfma_kernel<<<(N + 63) / 64, 256, 0, stream>>>(out, WT + 3 * D * D, bo, h, gamma, beta, out, N);
}

// Round 4
// 295.304 us; speedup vs baseline: 1.5482x; 1.0503x over previous
//
#include <hip/hip_runtime.h>
#include <hip/hip_bf16.h>
#include <math.h>

#define D 128
#define EPS 1e-12f

typedef __attribute__((ext_vector_type(8))) short bf16x8;
typedef __attribute__((ext_vector_type(4))) float f32x4;

// float -> bf16 round-to-nearest-even (finite inputs)
__device__ __forceinline__ unsigned short f2bf(float f) {
    unsigned int u = __float_as_uint(f);
    return (unsigned short)((u + 0x7fffu + ((u >> 16) & 1u)) >> 16);
}
__device__ __forceinline__ float bf2f_lo(unsigned int packed) {
    return __uint_as_float(packed << 16);
}
__device__ __forceinline__ float bf2f_hi(unsigned int packed) {
    return __uint_as_float(packed & 0xffff0000u);
}

// ---------------- CSR build ----------------

__global__ void count_kernel(const int* __restrict__ dst, int* __restrict__ counts, int E) {
    int e = (blockIdx.x * 256 + threadIdx.x) * 4;
    if (e >= E) return;
    if (e + 3 < E) {
        int4 d4 = *(const int4*)&dst[e];
        atomicAdd(&counts[d4.x], 1);
        atomicAdd(&counts[d4.y], 1);
        atomicAdd(&counts[d4.z], 1);
        atomicAdd(&counts[d4.w], 1);
    } else {
        for (int i = e; i < E; ++i) atomicAdd(&counts[dst[i]], 1);
    }
}

__device__ __forceinline__ int block_incl_scan256(int v, int tid, int* wsum) {
    int lane = tid & 63;
    int wid = tid >> 6;
#pragma unroll
    for (int off = 1; off < 64; off <<= 1) {
        int t = __shfl_up(v, off, 64);
        if (lane >= off) v += t;
    }
    if (lane == 63) wsum[wid] = v;
    __syncthreads();
#pragma unroll
    for (int w = 0; w < 4; ++w) {
        if (w < wid) v += wsum[w];
    }
    return v;
}

__global__ void scan1_kernel(const int* __restrict__ counts, int* __restrict__ offsets,
                             int* __restrict__ chunksum, int n) {
    __shared__ int wsum[4];
    int tid = threadIdx.x;
    int i = blockIdx.x * 256 + tid;
    int v = (i < n) ? counts[i] : 0;
    int incl = block_incl_scan256(v, tid, wsum);
    if (i < n) offsets[i + 1] = incl;
    if (tid == 255) chunksum[blockIdx.x] = incl;
}

__global__ void scan2_kernel(const int* __restrict__ chunksum, int* __restrict__ chunkbase, int nchunks) {
    __shared__ int wsum[4];
    int tid = threadIdx.x;
    int v = (tid < nchunks) ? chunksum[tid] : 0;
    int incl = block_incl_scan256(v, tid, wsum);
    if (tid < nchunks) chunkbase[tid] = incl - v;
}

__global__ void scan3_kernel(const int* __restrict__ counts, int* __restrict__ offsets,
                             const int* __restrict__ chunkbase, int* __restrict__ cursor, int n) {
    int i = blockIdx.x * 256 + threadIdx.x;
    if (i < n) {
        int fin = offsets[i + 1] + chunkbase[blockIdx.x];
        offsets[i + 1] = fin;
        cursor[i] = fin - counts[i];
        if (i == 0) offsets[0] = 0;
    }
}

__global__ void fill_kernel(const int* __restrict__ dst, const int* __restrict__ src,
                            int* __restrict__ cursor, int* __restrict__ psrc, int E) {
    int e = (blockIdx.x * 256 + threadIdx.x) * 4;
    if (e >= E) return;
    if (e + 3 < E) {
        int4 d4 = *(const int4*)&dst[e];
        int4 s4 = *(const int4*)&src[e];
        int p0 = atomicAdd(&cursor[d4.x], 1); psrc[p0] = s4.x;
        int p1 = atomicAdd(&cursor[d4.y], 1); psrc[p1] = s4.y;
        int p2 = atomicAdd(&cursor[d4.z], 1); psrc[p2] = s4.z;
        int p3 = atomicAdd(&cursor[d4.w], 1); psrc[p3] = s4.w;
    } else {
        for (int i = e; i < E; ++i) {
            int p = atomicAdd(&cursor[dst[i]], 1);
            psrc[p] = src[i];
        }
    }
}

// ---------------- W convert + transpose: WT[m][n][k] bf16 ----------------
__global__ __launch_bounds__(256) void wconv_kernel(
    const float* __restrict__ Wq, const float* __restrict__ Wk,
    const float* __restrict__ Wv, const float* __restrict__ Wo,
    unsigned short* __restrict__ WT) {
    __shared__ unsigned short tile[32][33];
    int m = blockIdx.y;
    const float* W = (m == 0) ? Wq : (m == 1) ? Wk : (m == 2) ? Wv : Wo;
    int r0 = (blockIdx.x & 3) * 32;   // k
    int c0 = (blockIdx.x >> 2) * 32;  // n
    int tid = threadIdx.x;
    int row = tid >> 3, c4 = (tid & 7) * 4;
    float4 v = *(const float4*)&W[(size_t)(r0 + row) * D + c0 + c4];
    tile[c4 + 0][row] = f2bf(v.x);
    tile[c4 + 1][row] = f2bf(v.y);
    tile[c4 + 2][row] = f2bf(v.z);
    tile[c4 + 3][row] = f2bf(v.w);
    __syncthreads();
    unsigned int lo = (unsigned int)tile[row][c4] | ((unsigned int)tile[row][c4 + 1] << 16);
    unsigned int hi = (unsigned int)tile[row][c4 + 2] | ((unsigned int)tile[row][c4 + 3] << 16);
    uint2 pk; pk.x = lo; pk.y = hi;
    *(uint2*)&WT[((size_t)m * D + (c0 + row)) * D + r0 + c4] = pk;
}

// ---------------- QKV projection via MFMA (all outputs bf16) ----------------
__global__ __launch_bounds__(256) void qkv_mfma_kernel(
    const float* __restrict__ h, const unsigned short* __restrict__ WT,
    const float* __restrict__ bq, const float* __restrict__ bk, const float* __restrict__ bv,
    unsigned short* __restrict__ Qb, unsigned short* __restrict__ Kb,
    unsigned short* __restrict__ Vb, int n) {
    __shared__ __align__(16) unsigned short hs[64][136];
    __shared__ __align__(16) unsigned short wt[128][136];
    int tid = threadIdx.x;
    int n0 = blockIdx.x * 64;
#pragma unroll
    for (int it = 0; it < 8; ++it) {
        int f4 = it * 256 + tid;
        int row = f4 >> 5;
        int c4 = (f4 & 31) * 4;
        float4 v = make_float4(0.f, 0.f, 0.f, 0.f);
        if (n0 + row < n) v = *(const float4*)&h[(size_t)(n0 + row) * D + c4];
        uint2 pk;
        pk.x = (unsigned int)f2bf(v.x) | ((unsigned int)f2bf(v.y) << 16);
        pk.y = (unsigned int)f2bf(v.z) | ((unsigned int)f2bf(v.w) << 16);
        *(uint2*)&hs[row][c4] = pk;
    }

    int lane = tid & 63, wid = tid >> 6;
    int quad = lane >> 4, l15 = lane & 15;
    int rbase = wid * 16;

    for (int m = 0; m < 3; ++m) {
#pragma unroll
        for (int it = 0; it < 8; ++it) {
            int idx = it * 256 + tid;
            int row = idx >> 4;
            int c8 = (idx & 15) * 8;
            *(uint4*)&wt[row][c8] = *(const uint4*)&WT[((size_t)m * D + row) * D + c8];
        }
        __syncthreads();

        bf16x8 af[4];
#pragma unroll
        for (int ks = 0; ks < 4; ++ks)
            af[ks] = *(const bf16x8*)&hs[rbase + l15][ks * 32 + quad * 8];

        const float* bias = (m == 0) ? bq : (m == 1) ? bk : bv;
        unsigned short* Ob = (m == 0) ? Qb : (m == 1) ? Kb : Vb;
#pragma unroll
        for (int ct = 0; ct < 8; ++ct) {
            f32x4 acc = {0.f, 0.f, 0.f, 0.f};
#pragma unroll
            for (int ks = 0; ks < 4; ++ks) {
                bf16x8 bf = *(const bf16x8*)&wt[ct * 16 + l15][ks * 32 + quad * 8];
                acc = __builtin_amdgcn_mfma_f32_16x16x32_bf16(af[ks], bf, acc, 0, 0, 0);
            }
            int col = ct * 16 + l15;
            float bb = bias[col];
#pragma unroll
            for (int r = 0; r < 4; ++r) {
                int row = n0 + rbase + quad * 4 + r;
                if (row < n) Ob[(size_t)row * D + col] = f2bf(acc[r] + bb);
            }
        }
        __syncthreads();
    }
}

// ---------------- Edge attention ----------------
// One wave per dst node. lane = j*16 + g: j = edge slot (0..3), g = dim-group (0..15, 8 dims each).
// Head h = g>>1 (16 dims = 2 groups). No max-subtraction (softmax shift-invariant; |score| small).
__global__ __launch_bounds__(256) void edge_attn_kernel(
    const unsigned short* __restrict__ Qb, const unsigned short* __restrict__ Kb,
    const unsigned short* __restrict__ Vb,
    const int* __restrict__ offsets, const int* __restrict__ psrc,
    unsigned short* __restrict__ aggb, int n) {
    int wave = (blockIdx.x * 256 + threadIdx.x) >> 6;
    int lane = threadIdx.x & 63;
    if (wave >= n) return;
    int start = offsets[wave], end = offsets[wave + 1];
    int j = lane >> 4, g = lane & 15;

    uint4 qu = *(const uint4*)&Qb[(size_t)wave * D + g * 8];
    float q0 = bf2f_lo(qu.x), q1 = bf2f_hi(qu.x);
    float q2 = bf2f_lo(qu.y), q3 = bf2f_hi(qu.y);
    float q4 = bf2f_lo(qu.z), q5 = bf2f_hi(qu.z);
    float q6 = bf2f_lo(qu.w), q7 = bf2f_hi(qu.w);

    float l = 0.f;
    float acc[8] = {};

    for (int base = start; base < end; base += 4) {
        int idx = base + j;
        bool valid = idx < end;
        int cidx = valid ? idx : (end - 1);
        int s = psrc[cidx];
        uint4 ku = *(const uint4*)&Kb[(size_t)s * D + g * 8];
        uint4 vu = *(const uint4*)&Vb[(size_t)s * D + g * 8];

        float sc = q0 * bf2f_lo(ku.x);
        sc = fmaf(q1, bf2f_hi(ku.x), sc);
        sc = fmaf(q2, bf2f_lo(ku.y), sc);
        sc = fmaf(q3, bf2f_hi(ku.y), sc);
        sc = fmaf(q4, bf2f_lo(ku.z), sc);
        sc = fmaf(q5, bf2f_hi(ku.z), sc);
        sc = fmaf(q6, bf2f_lo(ku.w), sc);
        sc = fmaf(q7, bf2f_hi(ku.w), sc);
        sc += __shfl_xor(sc, 1, 64);       // combine 2 dim-groups -> full 16-dim head score
        sc = valid ? sc : -1e30f;          // masked -> exp underflows to 0
        float p = __expf(sc);
        l += p;
        acc[0] = fmaf(p, bf2f_lo(vu.x), acc[0]);
        acc[1] = fmaf(p, bf2f_hi(vu.x), acc[1]);
        acc[2] = fmaf(p, bf2f_lo(vu.y), acc[2]);
        acc[3] = fmaf(p, bf2f_hi(vu.y), acc[3]);
        acc[4] = fmaf(p, bf2f_lo(vu.z), acc[4]);
        acc[5] = fmaf(p, bf2f_hi(vu.z), acc[5]);
        acc[6] = fmaf(p, bf2f_lo(vu.w), acc[6]);
        acc[7] = fmaf(p, bf2f_hi(vu.w), acc[7]);
    }

    // combine the 4 edge slots (lanes differing in bits 4,5)
#pragma unroll
    for (int off = 16; off <= 32; off <<= 1) {
        l += __shfl_xor(l, off, 64);
#pragma unroll
        for (int i = 0; i < 8; ++i) acc[i] += __shfl_xor(acc[i], off, 64);
    }
    float inv = (l > 0.f) ? 1.f / l : 0.f;
    if (j == 0) {
        uint4 o;
        o.x = (unsigned int)f2bf(acc[0] * inv) | ((unsigned int)f2bf(acc[1] * inv) << 16);
        o.y = (unsigned int)f2bf(acc[2] * inv) | ((unsigned int)f2bf(acc[3] * inv) << 16);
        o.z = (unsigned int)f2bf(acc[4] * inv) | ((unsigned int)f2bf(acc[5] * inv) << 16);
        o.w = (unsigned int)f2bf(acc[6] * inv) | ((unsigned int)f2bf(acc[7] * inv) << 16);
        *(uint4*)&aggb[(size_t)wave * D + g * 8] = o;
    }
}

// ---------------- Output GEMM (MFMA) + bias + residual + LayerNorm (in-register) ----------------
__global__ __launch_bounds__(256) void out_ln_mfma_kernel(
    const unsigned short* __restrict__ aggb, const unsigned short* __restrict__ WTo,
    const float* __restrict__ bo, const float* __restrict__ hres,
    const float* __restrict__ gamma, const float* __restrict__ beta,
    float* __restrict__ out, int n) {
    __shared__ __align__(16) unsigned short as_[64][136];
    __shared__ __align__(16) unsigned short wt[128][136];
    int tid = threadIdx.x;
    int n0 = blockIdx.x * 64;
    // stage agg (already bf16): 64 rows x 128 = 1024 uint4
#pragma unroll
    for (int it = 0; it < 4; ++it) {
        int idx = it * 256 + tid;
        int row = idx >> 4;
        int c8 = (idx & 15) * 8;
        uint4 v = make_uint4(0u, 0u, 0u, 0u);
        if (n0 + row < n) v = *(const uint4*)&aggb[(size_t)(n0 + row) * D + c8];
        *(uint4*)&as_[row][c8] = v;
    }
#pragma unroll
    for (int it = 0; it < 8; ++it) {
        int idx = it * 256 + tid;
        int row = idx >> 4;
        int c8 = (idx & 15) * 8;
        *(uint4*)&wt[row][c8] = *(const uint4*)&WTo[(size_t)row * D + c8];
    }
    __syncthreads();

    int lane = tid & 63, wid = tid >> 6;
    int quad = lane >> 4, l15 = lane & 15;
    int rbase = wid * 16;

    bf16x8 af[4];
#pragma unroll
    for (int ks = 0; ks < 4; ++ks)
        af[ks] = *(const bf16x8*)&as_[rbase + l15][ks * 32 + quad * 8];

    f32x4 acc[8];
#pragma unroll
    for (int ct = 0; ct < 8; ++ct) {
        acc[ct] = (f32x4){0.f, 0.f, 0.f, 0.f};
#pragma unroll
        for (int ks = 0; ks < 4; ++ks) {
            bf16x8 bf = *(const bf16x8*)&wt[ct * 16 + l15][ks * 32 + quad * 8];
            acc[ct] = __builtin_amdgcn_mfma_f32_16x16x32_bf16(af[ks], bf, acc[ct], 0, 0, 0);
        }
    }

    float bb[8], gg[8], be[8];
#pragma unroll
    for (int ct = 0; ct < 8; ++ct) {
        int col = ct * 16 + l15;
        bb[ct] = bo[col];
        gg[ct] = gamma[col];
        be[ct] = beta[col];
    }
#pragma unroll
    for (int ct = 0; ct < 8; ++ct) {
        int col = ct * 16 + l15;
#pragma unroll
        for (int r = 0; r < 4; ++r) {
            int row = n0 + rbase + quad * 4 + r;
            float hv = (row < n) ? hres[(size_t)row * D + col] : 0.f;
            acc[ct][r] = acc[ct][r] + bb[ct] + hv;
        }
    }

#pragma unroll
    for (int r = 0; r < 4; ++r) {
        float s1 = 0.f, s2 = 0.f;
#pragma unroll
        for (int ct = 0; ct < 8; ++ct) {
            float v = acc[ct][r];
            s1 += v;
            s2 += v * v;
        }
        s1 += __shfl_xor(s1, 1, 64); s2 += __shfl_xor(s2, 1, 64);
        s1 += __shfl_xor(s1, 2, 64); s2 += __shfl_xor(s2, 2, 64);
        s1 += __shfl_xor(s1, 4, 64); s2 += __shfl_xor(s2, 4, 64);
        s1 += __shfl_xor(s1, 8, 64); s2 += __shfl_xor(s2, 8, 64);
        float mu = s1 * (1.f / 128.f);
        float var = s2 * (1.f / 128.f) - mu * mu;
        float rs = rsqrtf(fmaxf(var, 0.f) + EPS);
        int row = n0 + rbase + quad * 4 + r;
        if (row < n) {
#pragma unroll
            for (int ct = 0; ct < 8; ++ct) {
                int col = ct * 16 + l15;
                out[(size_t)row * D + col] = (acc[ct][r] - mu) * rs * gg[ct] + be[ct];
            }
        }
    }
}

// ---------------- launch ----------------
extern "C" void kernel_launch(void* const* d_in, const int* in_sizes, int n_in,
                              void* d_out, int out_size, void* d_ws, size_t ws_size,
                              hipStream_t stream) {
    const float* h     = (const float*)d_in[0];
    const float* Wq    = (const float*)d_in[1];
    const float* bq    = (const float*)d_in[2];
    const float* Wk    = (const float*)d_in[3];
    const float* bk    = (const float*)d_in[4];
    const float* Wv    = (const float*)d_in[5];
    const float* bv    = (const float*)d_in[6];
    const float* Wo    = (const float*)d_in[7];
    const float* bo    = (const float*)d_in[8];
    const float* gamma = (const float*)d_in[9];
    const float* beta  = (const float*)d_in[10];
    const int* src     = (const int*)d_in[11];
    const int* dst     = (const int*)d_in[12];
    float* out = (float*)d_out;

    int N = in_sizes[0] / D;
    int E = in_sizes[11];

    // workspace layout (bf16 Q/K/V/agg)
    unsigned short* Qb = (unsigned short*)d_ws;
    unsigned short* Kb = Qb + (size_t)N * D;
    unsigned short* Vb = Kb + (size_t)N * D;
    unsigned short* Ab = Vb + (size_t)N * D;
    unsigned short* WT = Ab + (size_t)N * D;           // 4 * 128 * 128 bf16
    int* counts   = (int*)(WT + 4 * D * D);
    int* offsets  = counts + N;
    int* cursor   = offsets + (N + 1);
    int* chunksum = cursor + N;
    int* chunkbase = chunksum + 512;
    int* psrc     = chunkbase + 512;

    int nchunks = (N + 255) / 256;
    int e4blocks = ((E + 3) / 4 + 255) / 256;

    hipMemsetAsync(counts, 0, (size_t)N * sizeof(int), stream);
    wconv_kernel<<<dim3(16, 4), 256, 0, stream>>>(Wq, Wk, Wv, Wo, WT);
    count_kernel<<<e4blocks, 256, 0, stream>>>(dst, counts, E);
    scan1_kernel<<<nchunks, 256, 0, stream>>>(counts, offsets, chunksum, N);
    scan2_kernel<<<1, 256, 0, stream>>>(chunksum, chunkbase, nchunks);
    scan3_kernel<<<nchunks, 256, 0, stream>>>(counts, offsets, chunkbase, cursor, N);
    fill_kernel<<<e4blocks, 256, 0, stream>>>(dst, src, cursor, psrc, E);

    qkv_mfma_kernel<<<(N + 63) / 64, 256, 0, stream>>>(h, WT, bq, bk, bv, Qb, Kb, Vb, N);

    edge_attn_kernel<<<(N + 3) / 4, 256, 0, stream>>>(Qb, Kb, Vb, offsets, psrc, Ab, N);

    out_ln_mfma_kernel<<<(N + 63) / 64, 256, 0, stream>>>(Ab, WT + 3 * D * D, bo, h, gamma, beta, out, N);
}

// Round 5
// 292.579 us; speedup vs baseline: 1.5626x; 1.0093x over previous
//
#include <hip/hip_runtime.h>
#include <hip/hip_bf16.h>
#include <math.h>

#define D 128
#define EPS 1e-12f

typedef __attribute__((ext_vector_type(8))) short bf16x8;
typedef __attribute__((ext_vector_type(4))) float f32x4;

// float -> bf16 round-to-nearest-even (finite inputs)
__device__ __forceinline__ unsigned short f2bf(float f) {
    unsigned int u = __float_as_uint(f);
    return (unsigned short)((u + 0x7fffu + ((u >> 16) & 1u)) >> 16);
}
__device__ __forceinline__ float bf2f_lo(unsigned int packed) {
    return __uint_as_float(packed << 16);
}
__device__ __forceinline__ float bf2f_hi(unsigned int packed) {
    return __uint_as_float(packed & 0xffff0000u);
}

// ---------------- CSR build ----------------

// ticket[e] = arrival order of edge e at its dst bucket (also builds counts)
__global__ void ticket_kernel(const int* __restrict__ dst, int* __restrict__ counts,
                              int* __restrict__ ticket, int E) {
    int e = (blockIdx.x * 256 + threadIdx.x) * 4;
    if (e >= E) return;
    if (e + 3 < E) {
        int4 d4 = *(const int4*)&dst[e];
        int4 t4;
        t4.x = atomicAdd(&counts[d4.x], 1);
        t4.y = atomicAdd(&counts[d4.y], 1);
        t4.z = atomicAdd(&counts[d4.z], 1);
        t4.w = atomicAdd(&counts[d4.w], 1);
        *(int4*)&ticket[e] = t4;
    } else {
        for (int i = e; i < E; ++i) ticket[i] = atomicAdd(&counts[dst[i]], 1);
    }
}

// single-block fused scan: offsets[i+1] = prefix-inclusive(counts[0..i]), offsets[0]=0
__global__ __launch_bounds__(256) void scan_kernel(const int* __restrict__ counts,
                                                   int* __restrict__ offsets, int n) {
    __shared__ int wsums[4];
    __shared__ int s_running;
    int tid = threadIdx.x;
    int lane = tid & 63, wid = tid >> 6;
    if (tid == 0) s_running = 0;
    __syncthreads();
    int nT = (n + 2047) / 2048;
    for (int t = 0; t < nT; ++t) {
        int i0 = t * 2048 + tid * 8;
        int a[8];
        if (i0 + 7 < n) {
            int4 p0 = *(const int4*)&counts[i0];
            int4 p1 = *(const int4*)&counts[i0 + 4];
            a[0] = p0.x; a[1] = p0.y; a[2] = p0.z; a[3] = p0.w;
            a[4] = p1.x; a[5] = p1.y; a[6] = p1.z; a[7] = p1.w;
        } else {
#pragma unroll
            for (int k = 0; k < 8; ++k) a[k] = (i0 + k < n) ? counts[i0 + k] : 0;
        }
        int s = 0;
#pragma unroll
        for (int k = 0; k < 8; ++k) s += a[k];
        int v = s;
#pragma unroll
        for (int off = 1; off < 64; off <<= 1) {
            int tt = __shfl_up(v, off, 64);
            if (lane >= off) v += tt;
        }
        if (lane == 63) wsums[wid] = v;
        __syncthreads();
        int base = s_running;
#pragma unroll
        for (int w = 0; w < 4; ++w)
            if (w < wid) base += wsums[w];
        int run = base + v - s;   // exclusive prefix for this thread's first element
#pragma unroll
        for (int k = 0; k < 8; ++k) {
            run += a[k];
            if (i0 + k < n) offsets[i0 + k + 1] = run;
        }
        __syncthreads();
        if (tid == 255) s_running = base + v;
        __syncthreads();
    }
    if (tid == 0) offsets[0] = 0;
}

// pure scatter, no atomics: pos = offsets[dst] + ticket
__global__ void fill_kernel(const int* __restrict__ dst, const int* __restrict__ src,
                            const int* __restrict__ ticket, const int* __restrict__ offsets,
                            int* __restrict__ psrc, int E) {
    int e = (blockIdx.x * 256 + threadIdx.x) * 4;
    if (e >= E) return;
    if (e + 3 < E) {
        int4 d4 = *(const int4*)&dst[e];
        int4 s4 = *(const int4*)&src[e];
        int4 t4 = *(const int4*)&ticket[e];
        psrc[offsets[d4.x] + t4.x] = s4.x;
        psrc[offsets[d4.y] + t4.y] = s4.y;
        psrc[offsets[d4.z] + t4.z] = s4.z;
        psrc[offsets[d4.w] + t4.w] = s4.w;
    } else {
        for (int i = e; i < E; ++i) psrc[offsets[dst[i]] + ticket[i]] = src[i];
    }
}

// ---------------- W convert + transpose: WT[m][n][k] bf16 ----------------
__global__ __launch_bounds__(256) void wconv_kernel(
    const float* __restrict__ Wq, const float* __restrict__ Wk,
    const float* __restrict__ Wv, const float* __restrict__ Wo,
    unsigned short* __restrict__ WT) {
    __shared__ unsigned short tile[32][33];
    int m = blockIdx.y;
    const float* W = (m == 0) ? Wq : (m == 1) ? Wk : (m == 2) ? Wv : Wo;
    int r0 = (blockIdx.x & 3) * 32;   // k
    int c0 = (blockIdx.x >> 2) * 32;  // n
    int tid = threadIdx.x;
    int row = tid >> 3, c4 = (tid & 7) * 4;
    float4 v = *(const float4*)&W[(size_t)(r0 + row) * D + c0 + c4];
    tile[c4 + 0][row] = f2bf(v.x);
    tile[c4 + 1][row] = f2bf(v.y);
    tile[c4 + 2][row] = f2bf(v.z);
    tile[c4 + 3][row] = f2bf(v.w);
    __syncthreads();
    unsigned int lo = (unsigned int)tile[row][c4] | ((unsigned int)tile[row][c4 + 1] << 16);
    unsigned int hi = (unsigned int)tile[row][c4 + 2] | ((unsigned int)tile[row][c4 + 3] << 16);
    uint2 pk; pk.x = lo; pk.y = hi;
    *(uint2*)&WT[((size_t)m * D + (c0 + row)) * D + r0 + c4] = pk;
}

// ---------------- QKV projection via MFMA (all outputs bf16) ----------------
__global__ __launch_bounds__(256) void qkv_mfma_kernel(
    const float* __restrict__ h, const unsigned short* __restrict__ WT,
    const float* __restrict__ bq, const float* __restrict__ bk, const float* __restrict__ bv,
    unsigned short* __restrict__ Qb, unsigned short* __restrict__ Kb,
    unsigned short* __restrict__ Vb, int n) {
    __shared__ __align__(16) unsigned short hs[64][136];
    __shared__ __align__(16) unsigned short wt[128][136];
    int tid = threadIdx.x;
    int n0 = blockIdx.x * 64;
#pragma unroll
    for (int it = 0; it < 8; ++it) {
        int f4 = it * 256 + tid;
        int row = f4 >> 5;
        int c4 = (f4 & 31) * 4;
        float4 v = make_float4(0.f, 0.f, 0.f, 0.f);
        if (n0 + row < n) v = *(const float4*)&h[(size_t)(n0 + row) * D + c4];
        uint2 pk;
        pk.x = (unsigned int)f2bf(v.x) | ((unsigned int)f2bf(v.y) << 16);
        pk.y = (unsigned int)f2bf(v.z) | ((unsigned int)f2bf(v.w) << 16);
        *(uint2*)&hs[row][c4] = pk;
    }

    int lane = tid & 63, wid = tid >> 6;
    int quad = lane >> 4, l15 = lane & 15;
    int rbase = wid * 16;

    for (int m = 0; m < 3; ++m) {
#pragma unroll
        for (int it = 0; it < 8; ++it) {
            int idx = it * 256 + tid;
            int row = idx >> 4;
            int c8 = (idx & 15) * 8;
            *(uint4*)&wt[row][c8] = *(const uint4*)&WT[((size_t)m * D + row) * D + c8];
        }
        __syncthreads();

        bf16x8 af[4];
#pragma unroll
        for (int ks = 0; ks < 4; ++ks)
            af[ks] = *(const bf16x8*)&hs[rbase + l15][ks * 32 + quad * 8];

        const float* bias = (m == 0) ? bq : (m == 1) ? bk : bv;
        unsigned short* Ob = (m == 0) ? Qb : (m == 1) ? Kb : Vb;
#pragma unroll
        for (int ct = 0; ct < 8; ++ct) {
            f32x4 acc = {0.f, 0.f, 0.f, 0.f};
#pragma unroll
            for (int ks = 0; ks < 4; ++ks) {
                bf16x8 bf = *(const bf16x8*)&wt[ct * 16 + l15][ks * 32 + quad * 8];
                acc = __builtin_amdgcn_mfma_f32_16x16x32_bf16(af[ks], bf, acc, 0, 0, 0);
            }
            int col = ct * 16 + l15;
            float bb = bias[col];
#pragma unroll
            for (int r = 0; r < 4; ++r) {
                int row = n0 + rbase + quad * 4 + r;
                if (row < n) Ob[(size_t)row * D + col] = f2bf(acc[r] + bb);
            }
        }
        __syncthreads();
    }
}

// ---------------- Edge attention ----------------
// One wave per dst node. lane = j*8 + hd: j = edge slot (0..7), hd = head (0..7, 16 dims).
// Full head per lane -> no score shuffle. Next-iteration src indices prefetched.
__global__ __launch_bounds__(256) void edge_attn_kernel(
    const unsigned short* __restrict__ Qb, const unsigned short* __restrict__ Kb,
    const unsigned short* __restrict__ Vb,
    const int* __restrict__ offsets, const int* __restrict__ psrc,
    unsigned short* __restrict__ aggb, int n) {
    int wave = (blockIdx.x * 256 + threadIdx.x) >> 6;
    int lane = threadIdx.x & 63;
    if (wave >= n) return;
    int start = offsets[wave], end = offsets[wave + 1];
    int j = lane >> 3, hd = lane & 7;

    const unsigned short* qp = &Qb[(size_t)wave * D + hd * 16];
    uint4 qa = *(const uint4*)qp;
    uint4 qb = *(const uint4*)(qp + 8);
    float q[16];
    q[0] = bf2f_lo(qa.x);  q[1] = bf2f_hi(qa.x);
    q[2] = bf2f_lo(qa.y);  q[3] = bf2f_hi(qa.y);
    q[4] = bf2f_lo(qa.z);  q[5] = bf2f_hi(qa.z);
    q[6] = bf2f_lo(qa.w);  q[7] = bf2f_hi(qa.w);
    q[8] = bf2f_lo(qb.x);  q[9] = bf2f_hi(qb.x);
    q[10] = bf2f_lo(qb.y); q[11] = bf2f_hi(qb.y);
    q[12] = bf2f_lo(qb.z); q[13] = bf2f_hi(qb.z);
    q[14] = bf2f_lo(qb.w); q[15] = bf2f_hi(qb.w);

    float l = 0.f;
    float acc[16] = {};

    if (start < end) {
        int s = psrc[min(start + j, end - 1)];
        for (int base = start; base < end; base += 8) {
            const unsigned short* kp = &Kb[(size_t)s * D + hd * 16];
            const unsigned short* vp = &Vb[(size_t)s * D + hd * 16];
            uint4 ka = *(const uint4*)kp;
            uint4 kb2 = *(const uint4*)(kp + 8);
            uint4 va = *(const uint4*)vp;
            uint4 vb2 = *(const uint4*)(vp + 8);
            // prefetch next iteration's src index (independent of gathers above)
            int nb = base + 8;
            int sn = (nb < end) ? psrc[min(nb + j, end - 1)] : 0;
            bool valid = (base + j) < end;

            float sc = q[0] * bf2f_lo(ka.x);
            sc = fmaf(q[1], bf2f_hi(ka.x), sc);
            sc = fmaf(q[2], bf2f_lo(ka.y), sc);
            sc = fmaf(q[3], bf2f_hi(ka.y), sc);
            sc = fmaf(q[4], bf2f_lo(ka.z), sc);
            sc = fmaf(q[5], bf2f_hi(ka.z), sc);
            sc = fmaf(q[6], bf2f_lo(ka.w), sc);
            sc = fmaf(q[7], bf2f_hi(ka.w), sc);
            sc = fmaf(q[8], bf2f_lo(kb2.x), sc);
            sc = fmaf(q[9], bf2f_hi(kb2.x), sc);
            sc = fmaf(q[10], bf2f_lo(kb2.y), sc);
            sc = fmaf(q[11], bf2f_hi(kb2.y), sc);
            sc = fmaf(q[12], bf2f_lo(kb2.z), sc);
            sc = fmaf(q[13], bf2f_hi(kb2.z), sc);
            sc = fmaf(q[14], bf2f_lo(kb2.w), sc);
            sc = fmaf(q[15], bf2f_hi(kb2.w), sc);

            float p = valid ? __expf(sc) : 0.f;
            l += p;
            acc[0] = fmaf(p, bf2f_lo(va.x), acc[0]);
            acc[1] = fmaf(p, bf2f_hi(va.x), acc[1]);
            acc[2] = fmaf(p, bf2f_lo(va.y), acc[2]);
            acc[3] = fmaf(p, bf2f_hi(va.y), acc[3]);
            acc[4] = fmaf(p, bf2f_lo(va.z), acc[4]);
            acc[5] = fmaf(p, bf2f_hi(va.z), acc[5]);
            acc[6] = fmaf(p, bf2f_lo(va.w), acc[6]);
            acc[7] = fmaf(p, bf2f_hi(va.w), acc[7]);
            acc[8] = fmaf(p, bf2f_lo(vb2.x), acc[8]);
            acc[9] = fmaf(p, bf2f_hi(vb2.x), acc[9]);
            acc[10] = fmaf(p, bf2f_lo(vb2.y), acc[10]);
            acc[11] = fmaf(p, bf2f_hi(vb2.y), acc[11]);
            acc[12] = fmaf(p, bf2f_lo(vb2.z), acc[12]);
            acc[13] = fmaf(p, bf2f_hi(vb2.z), acc[13]);
            acc[14] = fmaf(p, bf2f_lo(vb2.w), acc[14]);
            acc[15] = fmaf(p, bf2f_hi(vb2.w), acc[15]);
            s = sn;
        }
    }

    // combine the 8 edge slots (lanes differing in bits 3,4,5)
#pragma unroll
    for (int off = 8; off <= 32; off <<= 1) {
        l += __shfl_xor(l, off, 64);
#pragma unroll
        for (int i = 0; i < 16; ++i) acc[i] += __shfl_xor(acc[i], off, 64);
    }
    float inv = (l > 0.f) ? 1.f / l : 0.f;
    if (j == 0) {
        uint4 o0, o1;
        o0.x = (unsigned int)f2bf(acc[0] * inv) | ((unsigned int)f2bf(acc[1] * inv) << 16);
        o0.y = (unsigned int)f2bf(acc[2] * inv) | ((unsigned int)f2bf(acc[3] * inv) << 16);
        o0.z = (unsigned int)f2bf(acc[4] * inv) | ((unsigned int)f2bf(acc[5] * inv) << 16);
        o0.w = (unsigned int)f2bf(acc[6] * inv) | ((unsigned int)f2bf(acc[7] * inv) << 16);
        o1.x = (unsigned int)f2bf(acc[8] * inv) | ((unsigned int)f2bf(acc[9] * inv) << 16);
        o1.y = (unsigned int)f2bf(acc[10] * inv) | ((unsigned int)f2bf(acc[11] * inv) << 16);
        o1.z = (unsigned int)f2bf(acc[12] * inv) | ((unsigned int)f2bf(acc[13] * inv) << 16);
        o1.w = (unsigned int)f2bf(acc[14] * inv) | ((unsigned int)f2bf(acc[15] * inv) << 16);
        unsigned short* op = &aggb[(size_t)wave * D + hd * 16];
        *(uint4*)op = o0;
        *(uint4*)(op + 8) = o1;
    }
}

// ---------------- Output GEMM (MFMA) + bias + residual + LayerNorm (in-register) ----------------
__global__ __launch_bounds__(256) void out_ln_mfma_kernel(
    const unsigned short* __restrict__ aggb, const unsigned short* __restrict__ WTo,
    const float* __restrict__ bo, const float* __restrict__ hres,
    const float* __restrict__ gamma, const float* __restrict__ beta,
    float* __restrict__ out, int n) {
    __shared__ __align__(16) unsigned short as_[64][136];
    __shared__ __align__(16) unsigned short wt[128][136];
    int tid = threadIdx.x;
    int n0 = blockIdx.x * 64;
#pragma unroll
    for (int it = 0; it < 4; ++it) {
        int idx = it * 256 + tid;
        int row = idx >> 4;
        int c8 = (idx & 15) * 8;
        uint4 v = make_uint4(0u, 0u, 0u, 0u);
        if (n0 + row < n) v = *(const uint4*)&aggb[(size_t)(n0 + row) * D + c8];
        *(uint4*)&as_[row][c8] = v;
    }
#pragma unroll
    for (int it = 0; it < 8; ++it) {
        int idx = it * 256 + tid;
        int row = idx >> 4;
        int c8 = (idx & 15) * 8;
        *(uint4*)&wt[row][c8] = *(const uint4*)&WTo[(size_t)row * D + c8];
    }
    __syncthreads();

    int lane = tid & 63, wid = tid >> 6;
    int quad = lane >> 4, l15 = lane & 15;
    int rbase = wid * 16;

    bf16x8 af[4];
#pragma unroll
    for (int ks = 0; ks < 4; ++ks)
        af[ks] = *(const bf16x8*)&as_[rbase + l15][ks * 32 + quad * 8];

    f32x4 acc[8];
#pragma unroll
    for (int ct = 0; ct < 8; ++ct) {
        acc[ct] = (f32x4){0.f, 0.f, 0.f, 0.f};
#pragma unroll
        for (int ks = 0; ks < 4; ++ks) {
            bf16x8 bf = *(const bf16x8*)&wt[ct * 16 + l15][ks * 32 + quad * 8];
            acc[ct] = __builtin_amdgcn_mfma_f32_16x16x32_bf16(af[ks], bf, acc[ct], 0, 0, 0);
        }
    }

    float bb[8], gg[8], be[8];
#pragma unroll
    for (int ct = 0; ct < 8; ++ct) {
        int col = ct * 16 + l15;
        bb[ct] = bo[col];
        gg[ct] = gamma[col];
        be[ct] = beta[col];
    }
#pragma unroll
    for (int ct = 0; ct < 8; ++ct) {
        int col = ct * 16 + l15;
#pragma unroll
        for (int r = 0; r < 4; ++r) {
            int row = n0 + rbase + quad * 4 + r;
            float hv = (row < n) ? hres[(size_t)row * D + col] : 0.f;
            acc[ct][r] = acc[ct][r] + bb[ct] + hv;
        }
    }

#pragma unroll
    for (int r = 0; r < 4; ++r) {
        float s1 = 0.f, s2 = 0.f;
#pragma unroll
        for (int ct = 0; ct < 8; ++ct) {
            float v = acc[ct][r];
            s1 += v;
            s2 += v * v;
        }
        s1 += __shfl_xor(s1, 1, 64); s2 += __shfl_xor(s2, 1, 64);
        s1 += __shfl_xor(s1, 2, 64); s2 += __shfl_xor(s2, 2, 64);
        s1 += __shfl_xor(s1, 4, 64); s2 += __shfl_xor(s2, 4, 64);
        s1 += __shfl_xor(s1, 8, 64); s2 += __shfl_xor(s2, 8, 64);
        float mu = s1 * (1.f / 128.f);
        float var = s2 * (1.f / 128.f) - mu * mu;
        float rs = rsqrtf(fmaxf(var, 0.f) + EPS);
        int row = n0 + rbase + quad * 4 + r;
        if (row < n) {
#pragma unroll
            for (int ct = 0; ct < 8; ++ct) {
                int col = ct * 16 + l15;
                out[(size_t)row * D + col] = (acc[ct][r] - mu) * rs * gg[ct] + be[ct];
            }
        }
    }
}

// ---------------- launch ----------------
extern "C" void kernel_launch(void* const* d_in, const int* in_sizes, int n_in,
                              void* d_out, int out_size, void* d_ws, size_t ws_size,
                              hipStream_t stream) {
    const float* h     = (const float*)d_in[0];
    const float* Wq    = (const float*)d_in[1];
    const float* bq    = (const float*)d_in[2];
    const float* Wk    = (const float*)d_in[3];
    const float* bk    = (const float*)d_in[4];
    const float* Wv    = (const float*)d_in[5];
    const float* bv    = (const float*)d_in[6];
    const float* Wo    = (const float*)d_in[7];
    const float* bo    = (const float*)d_in[8];
    const float* gamma = (const float*)d_in[9];
    const float* beta  = (const float*)d_in[10];
    const int* src     = (const int*)d_in[11];
    const int* dst     = (const int*)d_in[12];
    float* out = (float*)d_out;

    int N = in_sizes[0] / D;
    int E = in_sizes[11];

    // workspace layout (bf16 Q/K/V/agg)
    unsigned short* Qb = (unsigned short*)d_ws;
    unsigned short* Kb = Qb + (size_t)N * D;
    unsigned short* Vb = Kb + (size_t)N * D;
    unsigned short* Ab = Vb + (size_t)N * D;
    unsigned short* WT = Ab + (size_t)N * D;           // 4 * 128 * 128 bf16
    int* counts   = (int*)(WT + 4 * D * D);
    int* offsets  = counts + N;
    int* ticket   = offsets + (N + 1);
    int* psrc     = ticket + E;

    int e4blocks = ((E + 3) / 4 + 255) / 256;

    hipMemsetAsync(counts, 0, (size_t)N * sizeof(int), stream);
    wconv_kernel<<<dim3(16, 4), 256, 0, stream>>>(Wq, Wk, Wv, Wo, WT);
    ticket_kernel<<<e4blocks, 256, 0, stream>>>(dst, counts, ticket, E);
    scan_kernel<<<1, 256, 0, stream>>>(counts, offsets, N);
    fill_kernel<<<e4blocks, 256, 0, stream>>>(dst, src, ticket, offsets, psrc, E);

    qkv_mfma_kernel<<<(N + 63) / 64, 256, 0, stream>>>(h, WT, bq, bk, bv, Qb, Kb, Vb, N);

    edge_attn_kernel<<<(N + 3) / 4, 256, 0, stream>>>(Qb, Kb, Vb, offsets, psrc, Ab, N);

    out_ln_mfma_kernel<<<(N + 63) / 64, 256, 0, stream>>>(Ab, WT + 3 * D * D, bo, h, gamma, beta, out, N);
}

// Round 6
// 266.906 us; speedup vs baseline: 1.7129x; 1.0962x over previous
//
#include <hip/hip_runtime.h>
#include <hip/hip_bf16.h>
#include <math.h>

#define D 128
#define EPS 1e-12f

typedef __attribute__((ext_vector_type(8))) short bf16x8;
typedef __attribute__((ext_vector_type(4))) float f32x4;
typedef __attribute__((ext_vector_type(2))) float f32x2;

// float -> bf16 round-to-nearest-even (finite inputs)
__device__ __forceinline__ unsigned short f2bf(float f) {
    unsigned int u = __float_as_uint(f);
    return (unsigned short)((u + 0x7fffu + ((u >> 16) & 1u)) >> 16);
}
__device__ __forceinline__ float bf2f_lo(unsigned int packed) {
    return __uint_as_float(packed << 16);
}
__device__ __forceinline__ float bf2f_hi(unsigned int packed) {
    return __uint_as_float(packed & 0xffff0000u);
}
__device__ __forceinline__ unsigned char f2fp8(float f) {
    return (unsigned char)__builtin_amdgcn_cvt_pk_fp8_f32(f, f, 0, false);
}

// ---------------- merged: W transpose/convert (blocks 0..63) + ticket (blocks 64..) ----------------
__global__ __launch_bounds__(256) void prep_kernel(
    const float* __restrict__ Wq, const float* __restrict__ Wk,
    const float* __restrict__ Wv, const float* __restrict__ Wo,
    unsigned short* __restrict__ WT,
    const int* __restrict__ dst, int* __restrict__ counts,
    int* __restrict__ ticket, int E) {
    int bx = blockIdx.x;
    int tid = threadIdx.x;
    if (bx < 64) {
        __shared__ unsigned short tile[32][33];
        int m = bx >> 4;
        int t = bx & 15;
        const float* W = (m == 0) ? Wq : (m == 1) ? Wk : (m == 2) ? Wv : Wo;
        int r0 = (t & 3) * 32;   // k
        int c0 = (t >> 2) * 32;  // n
        int row = tid >> 3, c4 = (tid & 7) * 4;
        float4 v = *(const float4*)&W[(size_t)(r0 + row) * D + c0 + c4];
        tile[c4 + 0][row] = f2bf(v.x);
        tile[c4 + 1][row] = f2bf(v.y);
        tile[c4 + 2][row] = f2bf(v.z);
        tile[c4 + 3][row] = f2bf(v.w);
        __syncthreads();
        unsigned int lo = (unsigned int)tile[row][c4] | ((unsigned int)tile[row][c4 + 1] << 16);
        unsigned int hi = (unsigned int)tile[row][c4 + 2] | ((unsigned int)tile[row][c4 + 3] << 16);
        uint2 pk; pk.x = lo; pk.y = hi;
        *(uint2*)&WT[((size_t)m * D + (c0 + row)) * D + r0 + c4] = pk;
    } else {
        int e = ((bx - 64) * 256 + tid) * 4;
        if (e >= E) return;
        if (e + 3 < E) {
            int4 d4 = *(const int4*)&dst[e];
            int4 t4;
            t4.x = atomicAdd(&counts[d4.x], 1);
            t4.y = atomicAdd(&counts[d4.y], 1);
            t4.z = atomicAdd(&counts[d4.z], 1);
            t4.w = atomicAdd(&counts[d4.w], 1);
            *(int4*)&ticket[e] = t4;
        } else {
            for (int i = e; i < E; ++i) ticket[i] = atomicAdd(&counts[dst[i]], 1);
        }
    }
}

// ---------------- parallel 3-phase scan ----------------
__device__ __forceinline__ int block_incl_scan256(int v, int tid, int* wsum) {
    int lane = tid & 63;
    int wid = tid >> 6;
#pragma unroll
    for (int off = 1; off < 64; off <<= 1) {
        int t = __shfl_up(v, off, 64);
        if (lane >= off) v += t;
    }
    if (lane == 63) wsum[wid] = v;
    __syncthreads();
#pragma unroll
    for (int w = 0; w < 4; ++w)
        if (w < wid) v += wsum[w];
    return v;
}

__global__ void scan1_kernel(const int* __restrict__ counts, int* __restrict__ offsets,
                             int* __restrict__ chunksum, int n) {
    __shared__ int wsum[4];
    int tid = threadIdx.x;
    int i = blockIdx.x * 256 + tid;
    int v = (i < n) ? counts[i] : 0;
    int incl = block_incl_scan256(v, tid, wsum);
    if (i < n) offsets[i + 1] = incl;
    if (tid == 255) chunksum[blockIdx.x] = incl;
}

__global__ void scan2_kernel(const int* __restrict__ chunksum, int* __restrict__ chunkbase, int nchunks) {
    __shared__ int wsum[4];
    int tid = threadIdx.x;
    int v = (tid < nchunks) ? chunksum[tid] : 0;
    int incl = block_incl_scan256(v, tid, wsum);
    if (tid < nchunks) chunkbase[tid] = incl - v;
}

__global__ void scan3_kernel(int* __restrict__ offsets, const int* __restrict__ chunkbase, int n) {
    int i = blockIdx.x * 256 + threadIdx.x;
    if (i < n) {
        offsets[i + 1] += chunkbase[blockIdx.x];
        if (i == 0) offsets[0] = 0;
    }
}

// ---------------- merged: fill (blocks < e4blocks) + QKV MFMA (rest) ----------------
// fill: pure scatter, no atomics. qkv: LDS-free MFMA, A/B frags direct from global.
__global__ __launch_bounds__(256) void fill_qkv_kernel(
    const int* __restrict__ dst, const int* __restrict__ src,
    const int* __restrict__ ticket, const int* __restrict__ offsets,
    int* __restrict__ psrc, int E, int e4blocks,
    const float* __restrict__ h, const unsigned short* __restrict__ WT,
    const float* __restrict__ bq, const float* __restrict__ bk, const float* __restrict__ bv,
    unsigned short* __restrict__ Qb, unsigned char* __restrict__ K8,
    unsigned char* __restrict__ V8, int n) {
    int bx = blockIdx.x;
    int tid = threadIdx.x;
    if (bx < e4blocks) {
        int e = (bx * 256 + tid) * 4;
        if (e >= E) return;
        if (e + 3 < E) {
            int4 d4 = *(const int4*)&dst[e];
            int4 s4 = *(const int4*)&src[e];
            int4 t4 = *(const int4*)&ticket[e];
            psrc[offsets[d4.x] + t4.x] = s4.x;
            psrc[offsets[d4.y] + t4.y] = s4.y;
            psrc[offsets[d4.z] + t4.z] = s4.z;
            psrc[offsets[d4.w] + t4.w] = s4.w;
        } else {
            for (int i = e; i < E; ++i) psrc[offsets[dst[i]] + ticket[i]] = src[i];
        }
        return;
    }
    int bid = bx - e4blocks;
    int lane = tid & 63, wave = tid >> 6;
    int quad = lane >> 4, l15 = lane & 15;
    int rt = bid * 64 + wave * 16;          // this wave's 16-row tile

    // A-fragments: h rows rt+l15, k = ks*32 + quad*8 + j  (clamped row; OOB rows never stored)
    int rowA = min(rt + l15, n - 1);
    bf16x8 af[4];
#pragma unroll
    for (int ks = 0; ks < 4; ++ks) {
        const float* ap = &h[(size_t)rowA * D + ks * 32 + quad * 8];
        float4 a0 = *(const float4*)ap;
        float4 a1 = *(const float4*)(ap + 4);
        union { unsigned short u[8]; bf16x8 v; } pk;
        pk.u[0] = f2bf(a0.x); pk.u[1] = f2bf(a0.y);
        pk.u[2] = f2bf(a0.z); pk.u[3] = f2bf(a0.w);
        pk.u[4] = f2bf(a1.x); pk.u[5] = f2bf(a1.y);
        pk.u[6] = f2bf(a1.z); pk.u[7] = f2bf(a1.w);
        af[ks] = pk.v;
    }

    for (int m = 0; m < 3; ++m) {
        const float* bias = (m == 0) ? bq : (m == 1) ? bk : bv;
        f32x4 acc[8];
#pragma unroll
        for (int ct = 0; ct < 8; ++ct) {
            acc[ct] = (f32x4){0.f, 0.f, 0.f, 0.f};
#pragma unroll
            for (int ks = 0; ks < 4; ++ks) {
                bf16x8 bfr = *(const bf16x8*)&WT[((size_t)m * D + ct * 16 + l15) * D + ks * 32 + quad * 8];
                acc[ct] = __builtin_amdgcn_mfma_f32_16x16x32_bf16(af[ks], bfr, acc[ct], 0, 0, 0);
            }
        }
#pragma unroll
        for (int ct = 0; ct < 8; ++ct) {
            int col = ct * 16 + l15;
            float bb = bias[col];
#pragma unroll
            for (int r = 0; r < 4; ++r) {
                int row = rt + quad * 4 + r;
                if (row < n) {
                    float v = acc[ct][r] + bb;
                    if (m == 0)      Qb[(size_t)row * D + col] = f2bf(v);
                    else if (m == 1) K8[(size_t)row * D + col] = f2fp8(v);
                    else             V8[(size_t)row * D + col] = f2fp8(v);
                }
            }
        }
    }
}

// ---------------- Edge attention (fp8 K/V) ----------------
// One wave per dst node. lane = j*8 + hd: j = edge slot (0..7), hd = head (0..7, 16 dims).
__global__ __launch_bounds__(256) void edge_attn_kernel(
    const unsigned short* __restrict__ Qb, const unsigned char* __restrict__ K8,
    const unsigned char* __restrict__ V8,
    const int* __restrict__ offsets, const int* __restrict__ psrc,
    unsigned short* __restrict__ aggb, int n) {
    int wave = (blockIdx.x * 256 + threadIdx.x) >> 6;
    int lane = threadIdx.x & 63;
    if (wave >= n) return;
    int start = offsets[wave], end = offsets[wave + 1];
    int j = lane >> 3, hd = lane & 7;

    const unsigned short* qp = &Qb[(size_t)wave * D + hd * 16];
    uint4 qa = *(const uint4*)qp;
    uint4 qb = *(const uint4*)(qp + 8);
    float q[16];
    q[0] = bf2f_lo(qa.x);  q[1] = bf2f_hi(qa.x);
    q[2] = bf2f_lo(qa.y);  q[3] = bf2f_hi(qa.y);
    q[4] = bf2f_lo(qa.z);  q[5] = bf2f_hi(qa.z);
    q[6] = bf2f_lo(qa.w);  q[7] = bf2f_hi(qa.w);
    q[8] = bf2f_lo(qb.x);  q[9] = bf2f_hi(qb.x);
    q[10] = bf2f_lo(qb.y); q[11] = bf2f_hi(qb.y);
    q[12] = bf2f_lo(qb.z); q[13] = bf2f_hi(qb.z);
    q[14] = bf2f_lo(qb.w); q[15] = bf2f_hi(qb.w);

    float l = 0.f;
    float acc[16] = {};

    if (start < end) {
        int s = psrc[min(start + j, end - 1)];
        for (int base = start; base < end; base += 8) {
            uint4 ku = *(const uint4*)&K8[(size_t)s * D + hd * 16];
            uint4 vu = *(const uint4*)&V8[(size_t)s * D + hd * 16];
            int nb = base + 8;
            int sn = (nb < end) ? psrc[min(nb + j, end - 1)] : 0;
            bool valid = (base + j) < end;

            float kf[16], vf[16];
            {
                f32x2 t;
                t = __builtin_amdgcn_cvt_pk_f32_fp8(ku.x, false); kf[0] = t.x;  kf[1] = t.y;
                t = __builtin_amdgcn_cvt_pk_f32_fp8(ku.x, true);  kf[2] = t.x;  kf[3] = t.y;
                t = __builtin_amdgcn_cvt_pk_f32_fp8(ku.y, false); kf[4] = t.x;  kf[5] = t.y;
                t = __builtin_amdgcn_cvt_pk_f32_fp8(ku.y, true);  kf[6] = t.x;  kf[7] = t.y;
                t = __builtin_amdgcn_cvt_pk_f32_fp8(ku.z, false); kf[8] = t.x;  kf[9] = t.y;
                t = __builtin_amdgcn_cvt_pk_f32_fp8(ku.z, true);  kf[10] = t.x; kf[11] = t.y;
                t = __builtin_amdgcn_cvt_pk_f32_fp8(ku.w, false); kf[12] = t.x; kf[13] = t.y;
                t = __builtin_amdgcn_cvt_pk_f32_fp8(ku.w, true);  kf[14] = t.x; kf[15] = t.y;
                t = __builtin_amdgcn_cvt_pk_f32_fp8(vu.x, false); vf[0] = t.x;  vf[1] = t.y;
                t = __builtin_amdgcn_cvt_pk_f32_fp8(vu.x, true);  vf[2] = t.x;  vf[3] = t.y;
                t = __builtin_amdgcn_cvt_pk_f32_fp8(vu.y, false); vf[4] = t.x;  vf[5] = t.y;
                t = __builtin_amdgcn_cvt_pk_f32_fp8(vu.y, true);  vf[6] = t.x;  vf[7] = t.y;
                t = __builtin_amdgcn_cvt_pk_f32_fp8(vu.z, false); vf[8] = t.x;  vf[9] = t.y;
                t = __builtin_amdgcn_cvt_pk_f32_fp8(vu.z, true);  vf[10] = t.x; vf[11] = t.y;
                t = __builtin_amdgcn_cvt_pk_f32_fp8(vu.w, false); vf[12] = t.x; vf[13] = t.y;
                t = __builtin_amdgcn_cvt_pk_f32_fp8(vu.w, true);  vf[14] = t.x; vf[15] = t.y;
            }

            float sc = q[0] * kf[0];
#pragma unroll
            for (int i = 1; i < 16; ++i) sc = fmaf(q[i], kf[i], sc);

            float p = valid ? __expf(sc) : 0.f;
            l += p;
#pragma unroll
            for (int i = 0; i < 16; ++i) acc[i] = fmaf(p, vf[i], acc[i]);
            s = sn;
        }
    }

    // combine the 8 edge slots (lanes differing in bits 3,4,5)
#pragma unroll
    for (int off = 8; off <= 32; off <<= 1) {
        l += __shfl_xor(l, off, 64);
#pragma unroll
        for (int i = 0; i < 16; ++i) acc[i] += __shfl_xor(acc[i], off, 64);
    }
    float inv = (l > 0.f) ? 1.f / l : 0.f;
    if (j == 0) {
        uint4 o0, o1;
        o0.x = (unsigned int)f2bf(acc[0] * inv) | ((unsigned int)f2bf(acc[1] * inv) << 16);
        o0.y = (unsigned int)f2bf(acc[2] * inv) | ((unsigned int)f2bf(acc[3] * inv) << 16);
        o0.z = (unsigned int)f2bf(acc[4] * inv) | ((unsigned int)f2bf(acc[5] * inv) << 16);
        o0.w = (unsigned int)f2bf(acc[6] * inv) | ((unsigned int)f2bf(acc[7] * inv) << 16);
        o1.x = (unsigned int)f2bf(acc[8] * inv) | ((unsigned int)f2bf(acc[9] * inv) << 16);
        o1.y = (unsigned int)f2bf(acc[10] * inv) | ((unsigned int)f2bf(acc[11] * inv) << 16);
        o1.z = (unsigned int)f2bf(acc[12] * inv) | ((unsigned int)f2bf(acc[13] * inv) << 16);
        o1.w = (unsigned int)f2bf(acc[14] * inv) | ((unsigned int)f2bf(acc[15] * inv) << 16);
        unsigned short* op = &aggb[(size_t)wave * D + hd * 16];
        *(uint4*)op = o0;
        *(uint4*)(op + 8) = o1;
    }
}

// ---------------- Output GEMM (LDS-free MFMA) + bias + residual + LayerNorm ----------------
__global__ __launch_bounds__(256) void out_ln_mfma_kernel(
    const unsigned short* __restrict__ aggb, const unsigned short* __restrict__ WTo,
    const float* __restrict__ bo, const float* __restrict__ hres,
    const float* __restrict__ gamma, const float* __restrict__ beta,
    float* __restrict__ out, int n) {
    int tid = threadIdx.x;
    int lane = tid & 63, wave = tid >> 6;
    int quad = lane >> 4, l15 = lane & 15;
    int rt = blockIdx.x * 64 + wave * 16;

    int rowA = min(rt + l15, n - 1);
    bf16x8 af[4];
#pragma unroll
    for (int ks = 0; ks < 4; ++ks)
        af[ks] = *(const bf16x8*)&aggb[(size_t)rowA * D + ks * 32 + quad * 8];

    f32x4 acc[8];
#pragma unroll
    for (int ct = 0; ct < 8; ++ct) {
        acc[ct] = (f32x4){0.f, 0.f, 0.f, 0.f};
#pragma unroll
        for (int ks = 0; ks < 4; ++ks) {
            bf16x8 bfr = *(const bf16x8*)&WTo[((size_t)ct * 16 + l15) * D + ks * 32 + quad * 8];
            acc[ct] = __builtin_amdgcn_mfma_f32_16x16x32_bf16(af[ks], bfr, acc[ct], 0, 0, 0);
        }
    }

    float bb[8], gg[8], be[8];
#pragma unroll
    for (int ct = 0; ct < 8; ++ct) {
        int col = ct * 16 + l15;
        bb[ct] = bo[col];
        gg[ct] = gamma[col];
        be[ct] = beta[col];
    }
#pragma unroll
    for (int ct = 0; ct < 8; ++ct) {
        int col = ct * 16 + l15;
#pragma unroll
        for (int r = 0; r < 4; ++r) {
            int row = rt + quad * 4 + r;
            float hv = (row < n) ? hres[(size_t)row * D + col] : 0.f;
            acc[ct][r] = acc[ct][r] + bb[ct] + hv;
        }
    }

#pragma unroll
    for (int r = 0; r < 4; ++r) {
        float s1 = 0.f, s2 = 0.f;
#pragma unroll
        for (int ct = 0; ct < 8; ++ct) {
            float v = acc[ct][r];
            s1 += v;
            s2 += v * v;
        }
        s1 += __shfl_xor(s1, 1, 64); s2 += __shfl_xor(s2, 1, 64);
        s1 += __shfl_xor(s1, 2, 64); s2 += __shfl_xor(s2, 2, 64);
        s1 += __shfl_xor(s1, 4, 64); s2 += __shfl_xor(s2, 4, 64);
        s1 += __shfl_xor(s1, 8, 64); s2 += __shfl_xor(s2, 8, 64);
        float mu = s1 * (1.f / 128.f);
        float var = s2 * (1.f / 128.f) - mu * mu;
        float rs = rsqrtf(fmaxf(var, 0.f) + EPS);
        int row = rt + quad * 4 + r;
        if (row < n) {
#pragma unroll
            for (int ct = 0; ct < 8; ++ct) {
                int col = ct * 16 + l15;
                out[(size_t)row * D + col] = (acc[ct][r] - mu) * rs * gg[ct] + be[ct];
            }
        }
    }
}

// ---------------- launch ----------------
extern "C" void kernel_launch(void* const* d_in, const int* in_sizes, int n_in,
                              void* d_out, int out_size, void* d_ws, size_t ws_size,
                              hipStream_t stream) {
    const float* h     = (const float*)d_in[0];
    const float* Wq    = (const float*)d_in[1];
    const float* bq    = (const float*)d_in[2];
    const float* Wk    = (const float*)d_in[3];
    const float* bk    = (const float*)d_in[4];
    const float* Wv    = (const float*)d_in[5];
    const float* bv    = (const float*)d_in[6];
    const float* Wo    = (const float*)d_in[7];
    const float* bo    = (const float*)d_in[8];
    const float* gamma = (const float*)d_in[9];
    const float* beta  = (const float*)d_in[10];
    const int* src     = (const int*)d_in[11];
    const int* dst     = (const int*)d_in[12];
    float* out = (float*)d_out;

    int N = in_sizes[0] / D;
    int E = in_sizes[11];

    // workspace layout
    unsigned short* Qb = (unsigned short*)d_ws;               // N*D bf16
    unsigned short* Ab = Qb + (size_t)N * D;                  // N*D bf16
    unsigned short* WT = Ab + (size_t)N * D;                  // 4*D*D bf16
    unsigned char* K8  = (unsigned char*)(WT + 4 * D * D);    // N*D fp8
    unsigned char* V8  = K8 + (size_t)N * D;                  // N*D fp8
    int* counts   = (int*)(V8 + (size_t)N * D);
    int* offsets  = counts + N;
    int* chunksum = offsets + (N + 1);
    int* chunkbase = chunksum + 256;
    int* ticket   = chunkbase + 256;
    int* psrc     = ticket + E;

    int nchunks = (N + 255) / 256;
    int e4blocks = ((E + 3) / 4 + 255) / 256;
    int nqkv = (N + 63) / 64;

    hipMemsetAsync(counts, 0, (size_t)N * sizeof(int), stream);
    prep_kernel<<<64 + e4blocks, 256, 0, stream>>>(Wq, Wk, Wv, Wo, WT, dst, counts, ticket, E);
    scan1_kernel<<<nchunks, 256, 0, stream>>>(counts, offsets, chunksum, N);
    scan2_kernel<<<1, 256, 0, stream>>>(chunksum, chunkbase, nchunks);
    scan3_kernel<<<nchunks, 256, 0, stream>>>(offsets, chunkbase, N);
    fill_qkv_kernel<<<e4blocks + nqkv, 256, 0, stream>>>(
        dst, src, ticket, offsets, psrc, E, e4blocks,
        h, WT, bq, bk, bv, Qb, K8, V8, N);
    edge_attn_kernel<<<(N + 3) / 4, 256, 0, stream>>>(Qb, K8, V8, offsets, psrc, Ab, N);
    out_ln_mfma_kernel<<<(N + 63) / 64, 256, 0, stream>>>(Ab, WT + 3 * D * D, bo, h, gamma, beta, out, N);
}

// Round 7
// 247.878 us; speedup vs baseline: 1.8444x; 1.0768x over previous
//
#include <hip/hip_runtime.h>
#include <hip/hip_bf16.h>
#include <math.h>

#define D 128
#define EPS 1e-12f

typedef __attribute__((ext_vector_type(8))) short bf16x8;
typedef __attribute__((ext_vector_type(4))) float f32x4;
typedef __attribute__((ext_vector_type(2))) float f32x2;

// float -> bf16 round-to-nearest-even (finite inputs)
__device__ __forceinline__ unsigned short f2bf(float f) {
    unsigned int u = __float_as_uint(f);
    return (unsigned short)((u + 0x7fffu + ((u >> 16) & 1u)) >> 16);
}
__device__ __forceinline__ float bf2f_lo(unsigned int packed) {
    return __uint_as_float(packed << 16);
}
__device__ __forceinline__ float bf2f_hi(unsigned int packed) {
    return __uint_as_float(packed & 0xffff0000u);
}
__device__ __forceinline__ unsigned char f2fp8(float f) {
    return (unsigned char)__builtin_amdgcn_cvt_pk_fp8_f32(f, f, 0, false);
}

// ---------------- merged: W transpose/convert (blocks 0..63) + ticket (blocks 64..) ----------------
__global__ __launch_bounds__(256) void prep_kernel(
    const float* __restrict__ Wq, const float* __restrict__ Wk,
    const float* __restrict__ Wv, const float* __restrict__ Wo,
    unsigned short* __restrict__ WT,
    const int* __restrict__ dst, int* __restrict__ counts,
    int* __restrict__ ticket, int E) {
    int bx = blockIdx.x;
    int tid = threadIdx.x;
    if (bx < 64) {
        __shared__ unsigned short tile[32][33];
        int m = bx >> 4;
        int t = bx & 15;
        const float* W = (m == 0) ? Wq : (m == 1) ? Wk : (m == 2) ? Wv : Wo;
        int r0 = (t & 3) * 32;   // k
        int c0 = (t >> 2) * 32;  // n
        int row = tid >> 3, c4 = (tid & 7) * 4;
        float4 v = *(const float4*)&W[(size_t)(r0 + row) * D + c0 + c4];
        tile[c4 + 0][row] = f2bf(v.x);
        tile[c4 + 1][row] = f2bf(v.y);
        tile[c4 + 2][row] = f2bf(v.z);
        tile[c4 + 3][row] = f2bf(v.w);
        __syncthreads();
        unsigned int lo = (unsigned int)tile[row][c4] | ((unsigned int)tile[row][c4 + 1] << 16);
        unsigned int hi = (unsigned int)tile[row][c4 + 2] | ((unsigned int)tile[row][c4 + 3] << 16);
        uint2 pk; pk.x = lo; pk.y = hi;
        *(uint2*)&WT[((size_t)m * D + (c0 + row)) * D + r0 + c4] = pk;
    } else {
        int e = ((bx - 64) * 256 + tid) * 4;
        if (e >= E) return;
        if (e + 3 < E) {
            int4 d4 = *(const int4*)&dst[e];
            int4 t4;
            t4.x = atomicAdd(&counts[d4.x], 1);
            t4.y = atomicAdd(&counts[d4.y], 1);
            t4.z = atomicAdd(&counts[d4.z], 1);
            t4.w = atomicAdd(&counts[d4.w], 1);
            *(int4*)&ticket[e] = t4;
        } else {
            for (int i = e; i < E; ++i) ticket[i] = atomicAdd(&counts[dst[i]], 1);
        }
    }
}

// ---------------- parallel 3-phase scan ----------------
__device__ __forceinline__ int block_incl_scan256(int v, int tid, int* wsum) {
    int lane = tid & 63;
    int wid = tid >> 6;
#pragma unroll
    for (int off = 1; off < 64; off <<= 1) {
        int t = __shfl_up(v, off, 64);
        if (lane >= off) v += t;
    }
    if (lane == 63) wsum[wid] = v;
    __syncthreads();
#pragma unroll
    for (int w = 0; w < 4; ++w)
        if (w < wid) v += wsum[w];
    return v;
}

__global__ void scan1_kernel(const int* __restrict__ counts, int* __restrict__ offsets,
                             int* __restrict__ chunksum, int n) {
    __shared__ int wsum[4];
    int tid = threadIdx.x;
    int i = blockIdx.x * 256 + tid;
    int v = (i < n) ? counts[i] : 0;
    int incl = block_incl_scan256(v, tid, wsum);
    if (i < n) offsets[i + 1] = incl;
    if (tid == 255) chunksum[blockIdx.x] = incl;
}

__global__ void scan2_kernel(const int* __restrict__ chunksum, int* __restrict__ chunkbase, int nchunks) {
    __shared__ int wsum[4];
    int tid = threadIdx.x;
    int v = (tid < nchunks) ? chunksum[tid] : 0;
    int incl = block_incl_scan256(v, tid, wsum);
    if (tid < nchunks) chunkbase[tid] = incl - v;
}

__global__ void scan3_kernel(int* __restrict__ offsets, const int* __restrict__ chunkbase, int n) {
    int i = blockIdx.x * 256 + threadIdx.x;
    if (i < n) {
        offsets[i + 1] += chunkbase[blockIdx.x];
        if (i == 0) offsets[0] = 0;
    }
}

// ---------------- fill: pure scatter, no atomics ----------------
__global__ void fill_kernel(const int* __restrict__ dst, const int* __restrict__ src,
                            const int* __restrict__ ticket, const int* __restrict__ offsets,
                            int* __restrict__ psrc, int E) {
    int e = (blockIdx.x * 256 + threadIdx.x) * 4;
    if (e >= E) return;
    if (e + 3 < E) {
        int4 d4 = *(const int4*)&dst[e];
        int4 s4 = *(const int4*)&src[e];
        int4 t4 = *(const int4*)&ticket[e];
        psrc[offsets[d4.x] + t4.x] = s4.x;
        psrc[offsets[d4.y] + t4.y] = s4.y;
        psrc[offsets[d4.z] + t4.z] = s4.z;
        psrc[offsets[d4.w] + t4.w] = s4.w;
    } else {
        for (int i = e; i < E; ++i) psrc[offsets[dst[i]] + ticket[i]] = src[i];
    }
}

// ---------------- QKV MFMA: W staged in LDS (reused operand), A direct from global ----------------
__global__ __launch_bounds__(256) void qkv_mfma_kernel(
    const float* __restrict__ h, const unsigned short* __restrict__ WT,
    const float* __restrict__ bq, const float* __restrict__ bk, const float* __restrict__ bv,
    unsigned short* __restrict__ Qb, unsigned char* __restrict__ K8,
    unsigned char* __restrict__ V8, int n) {
    __shared__ __align__(16) unsigned short wt[128][136];
    int tid = threadIdx.x;
    int lane = tid & 63, wave = tid >> 6;
    int quad = lane >> 4, l15 = lane & 15;
    int rt = blockIdx.x * 64 + wave * 16;

    // A-fragments: h rows rt+l15 (clamped; OOB rows never stored), fp32 -> bf16
    int rowA = min(rt + l15, n - 1);
    bf16x8 af[4];
#pragma unroll
    for (int ks = 0; ks < 4; ++ks) {
        const float* ap = &h[(size_t)rowA * D + ks * 32 + quad * 8];
        float4 a0 = *(const float4*)ap;
        float4 a1 = *(const float4*)(ap + 4);
        union { unsigned short u[8]; bf16x8 v; } pk;
        pk.u[0] = f2bf(a0.x); pk.u[1] = f2bf(a0.y);
        pk.u[2] = f2bf(a0.z); pk.u[3] = f2bf(a0.w);
        pk.u[4] = f2bf(a1.x); pk.u[5] = f2bf(a1.y);
        pk.u[6] = f2bf(a1.z); pk.u[7] = f2bf(a1.w);
        af[ks] = pk.v;
    }

    for (int m = 0; m < 3; ++m) {
        // stage WT_m (bf16 [n][k], 128x128) into LDS
#pragma unroll
        for (int it = 0; it < 8; ++it) {
            int idx = it * 256 + tid;
            int row = idx >> 4;
            int c8 = (idx & 15) * 8;
            *(uint4*)&wt[row][c8] = *(const uint4*)&WT[((size_t)m * D + row) * D + c8];
        }
        __syncthreads();

        f32x4 acc[8];
#pragma unroll
        for (int ct = 0; ct < 8; ++ct) {
            acc[ct] = (f32x4){0.f, 0.f, 0.f, 0.f};
#pragma unroll
            for (int ks = 0; ks < 4; ++ks) {
                bf16x8 bfr = *(const bf16x8*)&wt[ct * 16 + l15][ks * 32 + quad * 8];
                acc[ct] = __builtin_amdgcn_mfma_f32_16x16x32_bf16(af[ks], bfr, acc[ct], 0, 0, 0);
            }
        }
        __syncthreads();   // wt consumed; next m may overwrite while stores drain

        const float* bias = (m == 0) ? bq : (m == 1) ? bk : bv;
#pragma unroll
        for (int ct = 0; ct < 8; ++ct) {
            int col = ct * 16 + l15;
            float bb = bias[col];
#pragma unroll
            for (int r = 0; r < 4; ++r) {
                int row = rt + quad * 4 + r;
                if (row < n) {
                    float v = acc[ct][r] + bb;
                    if (m == 0)      Qb[(size_t)row * D + col] = f2bf(v);
                    else if (m == 1) K8[(size_t)row * D + col] = f2fp8(v);
                    else             V8[(size_t)row * D + col] = f2fp8(v);
                }
            }
        }
    }
}

// ---------------- Edge attention (fp8 K/V) ----------------
// One wave per dst node. lane = j*8 + hd: j = edge slot (0..7), hd = head (0..7, 16 dims).
__global__ __launch_bounds__(256) void edge_attn_kernel(
    const unsigned short* __restrict__ Qb, const unsigned char* __restrict__ K8,
    const unsigned char* __restrict__ V8,
    const int* __restrict__ offsets, const int* __restrict__ psrc,
    unsigned short* __restrict__ aggb, int n) {
    int wave = (blockIdx.x * 256 + threadIdx.x) >> 6;
    int lane = threadIdx.x & 63;
    if (wave >= n) return;
    int start = offsets[wave], end = offsets[wave + 1];
    int j = lane >> 3, hd = lane & 7;

    const unsigned short* qp = &Qb[(size_t)wave * D + hd * 16];
    uint4 qa = *(const uint4*)qp;
    uint4 qb = *(const uint4*)(qp + 8);
    float q[16];
    q[0] = bf2f_lo(qa.x);  q[1] = bf2f_hi(qa.x);
    q[2] = bf2f_lo(qa.y);  q[3] = bf2f_hi(qa.y);
    q[4] = bf2f_lo(qa.z);  q[5] = bf2f_hi(qa.z);
    q[6] = bf2f_lo(qa.w);  q[7] = bf2f_hi(qa.w);
    q[8] = bf2f_lo(qb.x);  q[9] = bf2f_hi(qb.x);
    q[10] = bf2f_lo(qb.y); q[11] = bf2f_hi(qb.y);
    q[12] = bf2f_lo(qb.z); q[13] = bf2f_hi(qb.z);
    q[14] = bf2f_lo(qb.w); q[15] = bf2f_hi(qb.w);

    float l = 0.f;
    float acc[16] = {};

    if (start < end) {
        int s = psrc[min(start + j, end - 1)];
        for (int base = start; base < end; base += 8) {
            uint4 ku = *(const uint4*)&K8[(size_t)s * D + hd * 16];
            uint4 vu = *(const uint4*)&V8[(size_t)s * D + hd * 16];
            int nb = base + 8;
            int sn = (nb < end) ? psrc[min(nb + j, end - 1)] : 0;
            bool valid = (base + j) < end;

            float kf[16], vf[16];
            {
                f32x2 t;
                t = __builtin_amdgcn_cvt_pk_f32_fp8(ku.x, false); kf[0] = t.x;  kf[1] = t.y;
                t = __builtin_amdgcn_cvt_pk_f32_fp8(ku.x, true);  kf[2] = t.x;  kf[3] = t.y;
                t = __builtin_amdgcn_cvt_pk_f32_fp8(ku.y, false); kf[4] = t.x;  kf[5] = t.y;
                t = __builtin_amdgcn_cvt_pk_f32_fp8(ku.y, true);  kf[6] = t.x;  kf[7] = t.y;
                t = __builtin_amdgcn_cvt_pk_f32_fp8(ku.z, false); kf[8] = t.x;  kf[9] = t.y;
                t = __builtin_amdgcn_cvt_pk_f32_fp8(ku.z, true);  kf[10] = t.x; kf[11] = t.y;
                t = __builtin_amdgcn_cvt_pk_f32_fp8(ku.w, false); kf[12] = t.x; kf[13] = t.y;
                t = __builtin_amdgcn_cvt_pk_f32_fp8(ku.w, true);  kf[14] = t.x; kf[15] = t.y;
                t = __builtin_amdgcn_cvt_pk_f32_fp8(vu.x, false); vf[0] = t.x;  vf[1] = t.y;
                t = __builtin_amdgcn_cvt_pk_f32_fp8(vu.x, true);  vf[2] = t.x;  vf[3] = t.y;
                t = __builtin_amdgcn_cvt_pk_f32_fp8(vu.y, false); vf[4] = t.x;  vf[5] = t.y;
                t = __builtin_amdgcn_cvt_pk_f32_fp8(vu.y, true);  vf[6] = t.x;  vf[7] = t.y;
                t = __builtin_amdgcn_cvt_pk_f32_fp8(vu.z, false); vf[8] = t.x;  vf[9] = t.y;
                t = __builtin_amdgcn_cvt_pk_f32_fp8(vu.z, true);  vf[10] = t.x; vf[11] = t.y;
                t = __builtin_amdgcn_cvt_pk_f32_fp8(vu.w, false); vf[12] = t.x; vf[13] = t.y;
                t = __builtin_amdgcn_cvt_pk_f32_fp8(vu.w, true);  vf[14] = t.x; vf[15] = t.y;
            }

            float sc = q[0] * kf[0];
#pragma unroll
            for (int i = 1; i < 16; ++i) sc = fmaf(q[i], kf[i], sc);

            float p = valid ? __expf(sc) : 0.f;
            l += p;
#pragma unroll
            for (int i = 0; i < 16; ++i) acc[i] = fmaf(p, vf[i], acc[i]);
            s = sn;
        }
    }

    // combine the 8 edge slots (lanes differing in bits 3,4,5)
#pragma unroll
    for (int off = 8; off <= 32; off <<= 1) {
        l += __shfl_xor(l, off, 64);
#pragma unroll
        for (int i = 0; i < 16; ++i) acc[i] += __shfl_xor(acc[i], off, 64);
    }
    float inv = (l > 0.f) ? 1.f / l : 0.f;
    if (j == 0) {
        uint4 o0, o1;
        o0.x = (unsigned int)f2bf(acc[0] * inv) | ((unsigned int)f2bf(acc[1] * inv) << 16);
        o0.y = (unsigned int)f2bf(acc[2] * inv) | ((unsigned int)f2bf(acc[3] * inv) << 16);
        o0.z = (unsigned int)f2bf(acc[4] * inv) | ((unsigned int)f2bf(acc[5] * inv) << 16);
        o0.w = (unsigned int)f2bf(acc[6] * inv) | ((unsigned int)f2bf(acc[7] * inv) << 16);
        o1.x = (unsigned int)f2bf(acc[8] * inv) | ((unsigned int)f2bf(acc[9] * inv) << 16);
        o1.y = (unsigned int)f2bf(acc[10] * inv) | ((unsigned int)f2bf(acc[11] * inv) << 16);
        o1.z = (unsigned int)f2bf(acc[12] * inv) | ((unsigned int)f2bf(acc[13] * inv) << 16);
        o1.w = (unsigned int)f2bf(acc[14] * inv) | ((unsigned int)f2bf(acc[15] * inv) << 16);
        unsigned short* op = &aggb[(size_t)wave * D + hd * 16];
        *(uint4*)op = o0;
        *(uint4*)(op + 8) = o1;
    }
}

// ---------------- Output GEMM + bias + residual + LayerNorm (WTo is L1-resident) ----------------
__global__ __launch_bounds__(256) void out_ln_mfma_kernel(
    const unsigned short* __restrict__ aggb, const unsigned short* __restrict__ WTo,
    const float* __restrict__ bo, const float* __restrict__ hres,
    const float* __restrict__ gamma, const float* __restrict__ beta,
    float* __restrict__ out, int n) {
    int tid = threadIdx.x;
    int lane = tid & 63, wave = tid >> 6;
    int quad = lane >> 4, l15 = lane & 15;
    int rt = blockIdx.x * 64 + wave * 16;

    int rowA = min(rt + l15, n - 1);
    bf16x8 af[4];
#pragma unroll
    for (int ks = 0; ks < 4; ++ks)
        af[ks] = *(const bf16x8*)&aggb[(size_t)rowA * D + ks * 32 + quad * 8];

    f32x4 acc[8];
#pragma unroll
    for (int ct = 0; ct < 8; ++ct) {
        acc[ct] = (f32x4){0.f, 0.f, 0.f, 0.f};
#pragma unroll
        for (int ks = 0; ks < 4; ++ks) {
            bf16x8 bfr = *(const bf16x8*)&WTo[((size_t)ct * 16 + l15) * D + ks * 32 + quad * 8];
            acc[ct] = __builtin_amdgcn_mfma_f32_16x16x32_bf16(af[ks], bfr, acc[ct], 0, 0, 0);
        }
    }

    float bb[8], gg[8], be[8];
#pragma unroll
    for (int ct = 0; ct < 8; ++ct) {
        int col = ct * 16 + l15;
        bb[ct] = bo[col];
        gg[ct] = gamma[col];
        be[ct] = beta[col];
    }
#pragma unroll
    for (int ct = 0; ct < 8; ++ct) {
        int col = ct * 16 + l15;
#pragma unroll
        for (int r = 0; r < 4; ++r) {
            int row = rt + quad * 4 + r;
            float hv = (row < n) ? hres[(size_t)row * D + col] : 0.f;
            acc[ct][r] = acc[ct][r] + bb[ct] + hv;
        }
    }

#pragma unroll
    for (int r = 0; r < 4; ++r) {
        float s1 = 0.f, s2 = 0.f;
#pragma unroll
        for (int ct = 0; ct < 8; ++ct) {
            float v = acc[ct][r];
            s1 += v;
            s2 += v * v;
        }
        s1 += __shfl_xor(s1, 1, 64); s2 += __shfl_xor(s2, 1, 64);
        s1 += __shfl_xor(s1, 2, 64); s2 += __shfl_xor(s2, 2, 64);
        s1 += __shfl_xor(s1, 4, 64); s2 += __shfl_xor(s2, 4, 64);
        s1 += __shfl_xor(s1, 8, 64); s2 += __shfl_xor(s2, 8, 64);
        float mu = s1 * (1.f / 128.f);
        float var = s2 * (1.f / 128.f) - mu * mu;
        float rs = rsqrtf(fmaxf(var, 0.f) + EPS);
        int row = rt + quad * 4 + r;
        if (row < n) {
#pragma unroll
            for (int ct = 0; ct < 8; ++ct) {
                int col = ct * 16 + l15;
                out[(size_t)row * D + col] = (acc[ct][r] - mu) * rs * gg[ct] + be[ct];
            }
        }
    }
}

// ---------------- launch ----------------
extern "C" void kernel_launch(void* const* d_in, const int* in_sizes, int n_in,
                              void* d_out, int out_size, void* d_ws, size_t ws_size,
                              hipStream_t stream) {
    const float* h     = (const float*)d_in[0];
    const float* Wq    = (const float*)d_in[1];
    const float* bq    = (const float*)d_in[2];
    const float* Wk    = (const float*)d_in[3];
    const float* bk    = (const float*)d_in[4];
    const float* Wv    = (const float*)d_in[5];
    const float* bv    = (const float*)d_in[6];
    const float* Wo    = (const float*)d_in[7];
    const float* bo    = (const float*)d_in[8];
    const float* gamma = (const float*)d_in[9];
    const float* beta  = (const float*)d_in[10];
    const int* src     = (const int*)d_in[11];
    const int* dst     = (const int*)d_in[12];
    float* out = (float*)d_out;

    int N = in_sizes[0] / D;
    int E = in_sizes[11];

    // workspace layout
    unsigned short* Qb = (unsigned short*)d_ws;               // N*D bf16
    unsigned short* Ab = Qb + (size_t)N * D;                  // N*D bf16
    unsigned short* WT = Ab + (size_t)N * D;                  // 4*D*D bf16
    unsigned char* K8  = (unsigned char*)(WT + 4 * D * D);    // N*D fp8
    unsigned char* V8  = K8 + (size_t)N * D;                  // N*D fp8
    int* counts   = (int*)(V8 + (size_t)N * D);
    int* offsets  = counts + N;
    int* chunksum = offsets + (N + 1);
    int* chunkbase = chunksum + 256;
    int* ticket   = chunkbase + 256;
    int* psrc     = ticket + E;

    int nchunks = (N + 255) / 256;
    int e4blocks = ((E + 3) / 4 + 255) / 256;

    hipMemsetAsync(counts, 0, (size_t)N * sizeof(int), stream);
    prep_kernel<<<64 + e4blocks, 256, 0, stream>>>(Wq, Wk, Wv, Wo, WT, dst, counts, ticket, E);
    scan1_kernel<<<nchunks, 256, 0, stream>>>(counts, offsets, chunksum, N);
    scan2_kernel<<<1, 256, 0, stream>>>(chunksum, chunkbase, nchunks);
    scan3_kernel<<<nchunks, 256, 0, stream>>>(offsets, chunkbase, N);
    fill_kernel<<<e4blocks, 256, 0, stream>>>(dst, src, ticket, offsets, psrc, E);
    qkv_mfma_kernel<<<(N + 63) / 64, 256, 0, stream>>>(h, WT, bq, bk, bv, Qb, K8, V8, N);
    edge_attn_kernel<<<(N + 3) / 4, 256, 0, stream>>>(Qb, K8, V8, offsets, psrc, Ab, N);
    out_ln_mfma_kernel<<<(N + 63) / 64, 256, 0, stream>>>(Ab, WT + 3 * D * D, bo, h, gamma, beta, out, N);
}

// Round 8
// 229.660 us; speedup vs baseline: 1.9907x; 1.0793x over previous
//
#include <hip/hip_runtime.h>
#include <hip/hip_bf16.h>
#include <math.h>

#define D 128
#define EPS 1e-12f

typedef __attribute__((ext_vector_type(8))) short bf16x8;
typedef __attribute__((ext_vector_type(4))) float f32x4;
typedef __attribute__((ext_vector_type(2))) float f32x2;

// float -> bf16 round-to-nearest-even (finite inputs)
__device__ __forceinline__ unsigned short f2bf(float f) {
    unsigned int u = __float_as_uint(f);
    return (unsigned short)((u + 0x7fffu + ((u >> 16) & 1u)) >> 16);
}
__device__ __forceinline__ float bf2f_lo(unsigned int packed) {
    return __uint_as_float(packed << 16);
}
__device__ __forceinline__ float bf2f_hi(unsigned int packed) {
    return __uint_as_float(packed & 0xffff0000u);
}
__device__ __forceinline__ unsigned char f2fp8(float f) {
    return (unsigned char)__builtin_amdgcn_cvt_pk_fp8_f32(f, f, 0, false);
}

// ---------------- merged: W convert to MFMA-fragment order (blocks 0..63) + ticket ----------------
// Fragment order: WT[m*16384 + ((ct*4+ks)*64 + quad*16 + l15)*8 + j]
//   holds element (n = ct*16+l15, k = ks*32+quad*8+j) of W_m^T  (bf16)
__global__ __launch_bounds__(256) void prep_kernel(
    const float* __restrict__ Wq, const float* __restrict__ Wk,
    const float* __restrict__ Wv, const float* __restrict__ Wo,
    unsigned short* __restrict__ WT,
    const int* __restrict__ dst, int* __restrict__ counts,
    int* __restrict__ ticket, int E) {
    int bx = blockIdx.x;
    int tid = threadIdx.x;
    if (bx < 64) {
        __shared__ unsigned short tile[32][33];
        int m = bx >> 4;
        int t = bx & 15;
        const float* W = (m == 0) ? Wq : (m == 1) ? Wk : (m == 2) ? Wv : Wo;
        int r0 = (t & 3) * 32;   // k block
        int c0 = (t >> 2) * 32;  // n block
        int row = tid >> 3, c4 = (tid & 7) * 4;
        float4 v = *(const float4*)&W[(size_t)(r0 + row) * D + c0 + c4];
        tile[c4 + 0][row] = f2bf(v.x);
        tile[c4 + 1][row] = f2bf(v.y);
        tile[c4 + 2][row] = f2bf(v.z);
        tile[c4 + 3][row] = f2bf(v.w);
        __syncthreads();
        // this thread now owns elements (n = c0+row, k = r0+c4 .. +3)
        unsigned int lo = (unsigned int)tile[row][c4] | ((unsigned int)tile[row][c4 + 1] << 16);
        unsigned int hi = (unsigned int)tile[row][c4 + 2] | ((unsigned int)tile[row][c4 + 3] << 16);
        uint2 pk; pk.x = lo; pk.y = hi;
        int n = c0 + row;
        int ct = n >> 4, l15 = n & 15;
        int ks = t & 3;            // (r0+c4)>>5
        int quad = c4 >> 3;
        int j = c4 & 7;            // 0 or 4
        size_t off = (size_t)m * 16384 + (size_t)(((ct * 4 + ks) * 64) + quad * 16 + l15) * 8 + j;
        *(uint2*)&WT[off] = pk;
    } else {
        int e = ((bx - 64) * 256 + tid) * 4;
        if (e >= E) return;
        if (e + 3 < E) {
            int4 d4 = *(const int4*)&dst[e];
            int4 t4;
            t4.x = atomicAdd(&counts[d4.x], 1);
            t4.y = atomicAdd(&counts[d4.y], 1);
            t4.z = atomicAdd(&counts[d4.z], 1);
            t4.w = atomicAdd(&counts[d4.w], 1);
            *(int4*)&ticket[e] = t4;
        } else {
            for (int i = e; i < E; ++i) ticket[i] = atomicAdd(&counts[dst[i]], 1);
        }
    }
}

// ---------------- parallel 3-phase scan ----------------
__device__ __forceinline__ int block_incl_scan256(int v, int tid, int* wsum) {
    int lane = tid & 63;
    int wid = tid >> 6;
#pragma unroll
    for (int off = 1; off < 64; off <<= 1) {
        int t = __shfl_up(v, off, 64);
        if (lane >= off) v += t;
    }
    if (lane == 63) wsum[wid] = v;
    __syncthreads();
#pragma unroll
    for (int w = 0; w < 4; ++w)
        if (w < wid) v += wsum[w];
    return v;
}

__global__ void scan1_kernel(const int* __restrict__ counts, int* __restrict__ offsets,
                             int* __restrict__ chunksum, int n) {
    __shared__ int wsum[4];
    int tid = threadIdx.x;
    int i = blockIdx.x * 256 + tid;
    int v = (i < n) ? counts[i] : 0;
    int incl = block_incl_scan256(v, tid, wsum);
    if (i < n) offsets[i + 1] = incl;
    if (tid == 255) chunksum[blockIdx.x] = incl;
}

__global__ void scan2_kernel(const int* __restrict__ chunksum, int* __restrict__ chunkbase, int nchunks) {
    __shared__ int wsum[4];
    int tid = threadIdx.x;
    int v = (tid < nchunks) ? chunksum[tid] : 0;
    int incl = block_incl_scan256(v, tid, wsum);
    if (tid < nchunks) chunkbase[tid] = incl - v;
}

__global__ void scan3_kernel(int* __restrict__ offsets, const int* __restrict__ chunkbase, int n) {
    int i = blockIdx.x * 256 + threadIdx.x;
    if (i < n) {
        offsets[i + 1] += chunkbase[blockIdx.x];
        if (i == 0) offsets[0] = 0;
    }
}

// ---------------- fill: pure scatter, no atomics ----------------
__global__ void fill_kernel(const int* __restrict__ dst, const int* __restrict__ src,
                            const int* __restrict__ ticket, const int* __restrict__ offsets,
                            int* __restrict__ psrc, int E) {
    int e = (blockIdx.x * 256 + threadIdx.x) * 4;
    if (e >= E) return;
    if (e + 3 < E) {
        int4 d4 = *(const int4*)&dst[e];
        int4 s4 = *(const int4*)&src[e];
        int4 t4 = *(const int4*)&ticket[e];
        psrc[offsets[d4.x] + t4.x] = s4.x;
        psrc[offsets[d4.y] + t4.y] = s4.y;
        psrc[offsets[d4.z] + t4.z] = s4.z;
        psrc[offsets[d4.w] + t4.w] = s4.w;
    } else {
        for (int i = e; i < E; ++i) psrc[offsets[dst[i]] + ticket[i]] = src[i];
    }
}

// ---------------- QKV MFMA: frag-ordered W in LDS (conflict-free), A direct from global ----------------
__global__ __launch_bounds__(256) void qkv_mfma_kernel(
    const float* __restrict__ h, const unsigned short* __restrict__ WT,
    const float* __restrict__ bq, const float* __restrict__ bk, const float* __restrict__ bv,
    unsigned short* __restrict__ Qb, unsigned char* __restrict__ K8,
    unsigned char* __restrict__ V8, int n) {
    __shared__ __align__(16) unsigned short wt[16384];   // 32 KB, frag-ordered
    int tid = threadIdx.x;
    int lane = tid & 63, wave = tid >> 6;
    int quad = lane >> 4, l15 = lane & 15;
    int rt = blockIdx.x * 64 + wave * 16;

    // A-fragments: h rows rt+l15 (clamped; OOB rows never stored), fp32 -> bf16
    int rowA = min(rt + l15, n - 1);
    bf16x8 af[4];
#pragma unroll
    for (int ks = 0; ks < 4; ++ks) {
        const float* ap = &h[(size_t)rowA * D + ks * 32 + quad * 8];
        float4 a0 = *(const float4*)ap;
        float4 a1 = *(const float4*)(ap + 4);
        union { unsigned short u[8]; bf16x8 v; } pk;
        pk.u[0] = f2bf(a0.x); pk.u[1] = f2bf(a0.y);
        pk.u[2] = f2bf(a0.z); pk.u[3] = f2bf(a0.w);
        pk.u[4] = f2bf(a1.x); pk.u[5] = f2bf(a1.y);
        pk.u[6] = f2bf(a1.z); pk.u[7] = f2bf(a1.w);
        af[ks] = pk.v;
    }

    for (int m = 0; m < 3; ++m) {
        // linear 32 KB copy: lane-consecutive uint4, conflict-free both sides
#pragma unroll
        for (int it = 0; it < 8; ++it) {
            int idx = it * 256 + tid;
            *(uint4*)&wt[idx * 8] = *(const uint4*)&WT[(size_t)m * 16384 + idx * 8];
        }
        __syncthreads();

        f32x4 acc[8];
#pragma unroll
        for (int ct = 0; ct < 8; ++ct) {
            acc[ct] = (f32x4){0.f, 0.f, 0.f, 0.f};
#pragma unroll
            for (int ks = 0; ks < 4; ++ks) {
                // frag read: base + lane*16B  -> zero bank conflicts
                bf16x8 bfr = *(const bf16x8*)&wt[((ct * 4 + ks) * 64 + lane) * 8];
                acc[ct] = __builtin_amdgcn_mfma_f32_16x16x32_bf16(af[ks], bfr, acc[ct], 0, 0, 0);
            }
        }
        __syncthreads();   // wt consumed before next m overwrites

        const float* bias = (m == 0) ? bq : (m == 1) ? bk : bv;
#pragma unroll
        for (int ct = 0; ct < 8; ++ct) {
            int col = ct * 16 + l15;
            float bb = bias[col];
#pragma unroll
            for (int r = 0; r < 4; ++r) {
                int row = rt + quad * 4 + r;
                if (row < n) {
                    float v = acc[ct][r] + bb;
                    if (m == 0)      Qb[(size_t)row * D + col] = f2bf(v);
                    else if (m == 1) K8[(size_t)row * D + col] = f2fp8(v);
                    else             V8[(size_t)row * D + col] = f2fp8(v);
                }
            }
        }
    }
}

// ---------------- Edge attention (fp8 K/V) ----------------
// One wave per dst node. lane = j*8 + hd: j = edge slot (0..7), hd = head (0..7, 16 dims).
__global__ __launch_bounds__(256) void edge_attn_kernel(
    const unsigned short* __restrict__ Qb, const unsigned char* __restrict__ K8,
    const unsigned char* __restrict__ V8,
    const int* __restrict__ offsets, const int* __restrict__ psrc,
    unsigned short* __restrict__ aggb, int n) {
    int wave = (blockIdx.x * 256 + threadIdx.x) >> 6;
    int lane = threadIdx.x & 63;
    if (wave >= n) return;
    int start = offsets[wave], end = offsets[wave + 1];
    int j = lane >> 3, hd = lane & 7;

    const unsigned short* qp = &Qb[(size_t)wave * D + hd * 16];
    uint4 qa = *(const uint4*)qp;
    uint4 qb = *(const uint4*)(qp + 8);
    float q[16];
    q[0] = bf2f_lo(qa.x);  q[1] = bf2f_hi(qa.x);
    q[2] = bf2f_lo(qa.y);  q[3] = bf2f_hi(qa.y);
    q[4] = bf2f_lo(qa.z);  q[5] = bf2f_hi(qa.z);
    q[6] = bf2f_lo(qa.w);  q[7] = bf2f_hi(qa.w);
    q[8] = bf2f_lo(qb.x);  q[9] = bf2f_hi(qb.x);
    q[10] = bf2f_lo(qb.y); q[11] = bf2f_hi(qb.y);
    q[12] = bf2f_lo(qb.z); q[13] = bf2f_hi(qb.z);
    q[14] = bf2f_lo(qb.w); q[15] = bf2f_hi(qb.w);

    float l = 0.f;
    float acc[16] = {};

    if (start < end) {
        int s = psrc[min(start + j, end - 1)];
        for (int base = start; base < end; base += 8) {
            uint4 ku = *(const uint4*)&K8[(size_t)s * D + hd * 16];
            uint4 vu = *(const uint4*)&V8[(size_t)s * D + hd * 16];
            int nb = base + 8;
            int sn = (nb < end) ? psrc[min(nb + j, end - 1)] : 0;
            bool valid = (base + j) < end;

            float kf[16], vf[16];
            {
                f32x2 t;
                t = __builtin_amdgcn_cvt_pk_f32_fp8(ku.x, false); kf[0] = t.x;  kf[1] = t.y;
                t = __builtin_amdgcn_cvt_pk_f32_fp8(ku.x, true);  kf[2] = t.x;  kf[3] = t.y;
                t = __builtin_amdgcn_cvt_pk_f32_fp8(ku.y, false); kf[4] = t.x;  kf[5] = t.y;
                t = __builtin_amdgcn_cvt_pk_f32_fp8(ku.y, true);  kf[6] = t.x;  kf[7] = t.y;
                t = __builtin_amdgcn_cvt_pk_f32_fp8(ku.z, false); kf[8] = t.x;  kf[9] = t.y;
                t = __builtin_amdgcn_cvt_pk_f32_fp8(ku.z, true);  kf[10] = t.x; kf[11] = t.y;
                t = __builtin_amdgcn_cvt_pk_f32_fp8(ku.w, false); kf[12] = t.x; kf[13] = t.y;
                t = __builtin_amdgcn_cvt_pk_f32_fp8(ku.w, true);  kf[14] = t.x; kf[15] = t.y;
                t = __builtin_amdgcn_cvt_pk_f32_fp8(vu.x, false); vf[0] = t.x;  vf[1] = t.y;
                t = __builtin_amdgcn_cvt_pk_f32_fp8(vu.x, true);  vf[2] = t.x;  vf[3] = t.y;
                t = __builtin_amdgcn_cvt_pk_f32_fp8(vu.y, false); vf[4] = t.x;  vf[5] = t.y;
                t = __builtin_amdgcn_cvt_pk_f32_fp8(vu.y, true);  vf[6] = t.x;  vf[7] = t.y;
                t = __builtin_amdgcn_cvt_pk_f32_fp8(vu.z, false); vf[8] = t.x;  vf[9] = t.y;
                t = __builtin_amdgcn_cvt_pk_f32_fp8(vu.z, true);  vf[10] = t.x; vf[11] = t.y;
                t = __builtin_amdgcn_cvt_pk_f32_fp8(vu.w, false); vf[12] = t.x; vf[13] = t.y;
                t = __builtin_amdgcn_cvt_pk_f32_fp8(vu.w, true);  vf[14] = t.x; vf[15] = t.y;
            }

            float sc = q[0] * kf[0];
#pragma unroll
            for (int i = 1; i < 16; ++i) sc = fmaf(q[i], kf[i], sc);

            float p = valid ? __expf(sc) : 0.f;
            l += p;
#pragma unroll
            for (int i = 0; i < 16; ++i) acc[i] = fmaf(p, vf[i], acc[i]);
            s = sn;
        }
    }

    // combine the 8 edge slots (lanes differing in bits 3,4,5)
#pragma unroll
    for (int off = 8; off <= 32; off <<= 1) {
        l += __shfl_xor(l, off, 64);
#pragma unroll
        for (int i = 0; i < 16; ++i) acc[i] += __shfl_xor(acc[i], off, 64);
    }
    float inv = (l > 0.f) ? 1.f / l : 0.f;
    if (j == 0) {
        uint4 o0, o1;
        o0.x = (unsigned int)f2bf(acc[0] * inv) | ((unsigned int)f2bf(acc[1] * inv) << 16);
        o0.y = (unsigned int)f2bf(acc[2] * inv) | ((unsigned int)f2bf(acc[3] * inv) << 16);
        o0.z = (unsigned int)f2bf(acc[4] * inv) | ((unsigned int)f2bf(acc[5] * inv) << 16);
        o0.w = (unsigned int)f2bf(acc[6] * inv) | ((unsigned int)f2bf(acc[7] * inv) << 16);
        o1.x = (unsigned int)f2bf(acc[8] * inv) | ((unsigned int)f2bf(acc[9] * inv) << 16);
        o1.y = (unsigned int)f2bf(acc[10] * inv) | ((unsigned int)f2bf(acc[11] * inv) << 16);
        o1.z = (unsigned int)f2bf(acc[12] * inv) | ((unsigned int)f2bf(acc[13] * inv) << 16);
        o1.w = (unsigned int)f2bf(acc[14] * inv) | ((unsigned int)f2bf(acc[15] * inv) << 16);
        unsigned short* op = &aggb[(size_t)wave * D + hd * 16];
        *(uint4*)op = o0;
        *(uint4*)(op + 8) = o1;
    }
}

// ---------------- Output GEMM + bias + residual + LayerNorm (frag-ordered WTo, coalesced) ----------------
__global__ __launch_bounds__(256) void out_ln_mfma_kernel(
    const unsigned short* __restrict__ aggb, const unsigned short* __restrict__ WTo,
    const float* __restrict__ bo, const float* __restrict__ hres,
    const float* __restrict__ gamma, const float* __restrict__ beta,
    float* __restrict__ out, int n) {
    int tid = threadIdx.x;
    int lane = tid & 63, wave = tid >> 6;
    int quad = lane >> 4, l15 = lane & 15;
    int rt = blockIdx.x * 64 + wave * 16;

    int rowA = min(rt + l15, n - 1);
    bf16x8 af[4];
#pragma unroll
    for (int ks = 0; ks < 4; ++ks)
        af[ks] = *(const bf16x8*)&aggb[(size_t)rowA * D + ks * 32 + quad * 8];

    f32x4 acc[8];
#pragma unroll
    for (int ct = 0; ct < 8; ++ct) {
        acc[ct] = (f32x4){0.f, 0.f, 0.f, 0.f};
#pragma unroll
        for (int ks = 0; ks < 4; ++ks) {
            bf16x8 bfr = *(const bf16x8*)&WTo[(size_t)((ct * 4 + ks) * 64 + lane) * 8];
            acc[ct] = __builtin_amdgcn_mfma_f32_16x16x32_bf16(af[ks], bfr, acc[ct], 0, 0, 0);
        }
    }

    float bb[8], gg[8], be[8];
#pragma unroll
    for (int ct = 0; ct < 8; ++ct) {
        int col = ct * 16 + l15;
        bb[ct] = bo[col];
        gg[ct] = gamma[col];
        be[ct] = beta[col];
    }
#pragma unroll
    for (int ct = 0; ct < 8; ++ct) {
        int col = ct * 16 + l15;
#pragma unroll
        for (int r = 0; r < 4; ++r) {
            int row = rt + quad * 4 + r;
            float hv = (row < n) ? hres[(size_t)row * D + col] : 0.f;
            acc[ct][r] = acc[ct][r] + bb[ct] + hv;
        }
    }

#pragma unroll
    for (int r = 0; r < 4; ++r) {
        float s1 = 0.f, s2 = 0.f;
#pragma unroll
        for (int ct = 0; ct < 8; ++ct) {
            float v = acc[ct][r];
            s1 += v;
            s2 += v * v;
        }
        s1 += __shfl_xor(s1, 1, 64); s2 += __shfl_xor(s2, 1, 64);
        s1 += __shfl_xor(s1, 2, 64); s2 += __shfl_xor(s2, 2, 64);
        s1 += __shfl_xor(s1, 4, 64); s2 += __shfl_xor(s2, 4, 64);
        s1 += __shfl_xor(s1, 8, 64); s2 += __shfl_xor(s2, 8, 64);
        float mu = s1 * (1.f / 128.f);
        float var = s2 * (1.f / 128.f) - mu * mu;
        float rs = rsqrtf(fmaxf(var, 0.f) + EPS);
        int row = rt + quad * 4 + r;
        if (row < n) {
#pragma unroll
            for (int ct = 0; ct < 8; ++ct) {
                int col = ct * 16 + l15;
                out[(size_t)row * D + col] = (acc[ct][r] - mu) * rs * gg[ct] + be[ct];
            }
        }
    }
}

// ---------------- launch ----------------
extern "C" void kernel_launch(void* const* d_in, const int* in_sizes, int n_in,
                              void* d_out, int out_size, void* d_ws, size_t ws_size,
                              hipStream_t stream) {
    const float* h     = (const float*)d_in[0];
    const float* Wq    = (const float*)d_in[1];
    const float* bq    = (const float*)d_in[2];
    const float* Wk    = (const float*)d_in[3];
    const float* bk    = (const float*)d_in[4];
    const float* Wv    = (const float*)d_in[5];
    const float* bv    = (const float*)d_in[6];
    const float* Wo    = (const float*)d_in[7];
    const float* bo    = (const float*)d_in[8];
    const float* gamma = (const float*)d_in[9];
    const float* beta  = (const float*)d_in[10];
    const int* src     = (const int*)d_in[11];
    const int* dst     = (const int*)d_in[12];
    float* out = (float*)d_out;

    int N = in_sizes[0] / D;
    int E = in_sizes[11];

    // workspace layout
    unsigned short* Qb = (unsigned short*)d_ws;               // N*D bf16
    unsigned short* Ab = Qb + (size_t)N * D;                  // N*D bf16
    unsigned short* WT = Ab + (size_t)N * D;                  // 4*D*D bf16 (frag order)
    unsigned char* K8  = (unsigned char*)(WT + 4 * D * D);    // N*D fp8
    unsigned char* V8  = K8 + (size_t)N * D;                  // N*D fp8
    int* counts   = (int*)(V8 + (size_t)N * D);
    int* offsets  = counts + N;
    int* chunksum = offsets + (N + 1);
    int* chunkbase = chunksum + 256;
    int* ticket   = chunkbase + 256;
    int* psrc     = ticket + E;

    int nchunks = (N + 255) / 256;
    int e4blocks = ((E + 3) / 4 + 255) / 256;

    hipMemsetAsync(counts, 0, (size_t)N * sizeof(int), stream);
    prep_kernel<<<64 + e4blocks, 256, 0, stream>>>(Wq, Wk, Wv, Wo, WT, dst, counts, ticket, E);
    scan1_kernel<<<nchunks, 256, 0, stream>>>(counts, offsets, chunksum, N);
    scan2_kernel<<<1, 256, 0, stream>>>(chunksum, chunkbase, nchunks);
    scan3_kernel<<<nchunks, 256, 0, stream>>>(offsets, chunkbase, N);
    fill_kernel<<<e4blocks, 256, 0, stream>>>(dst, src, ticket, offsets, psrc, E);
    qkv_mfma_kernel<<<(N + 63) / 64, 256, 0, stream>>>(h, WT, bq, bk, bv, Qb, K8, V8, N);
    edge_attn_kernel<<<(N + 3) / 4, 256, 0, stream>>>(Qb, K8, V8, offsets, psrc, Ab, N);
    out_ln_mfma_kernel<<<(N + 63) / 64, 256, 0, stream>>>(Ab, WT + 3 * D * D, bo, h, gamma, beta, out, N);
}